// Round 14
// baseline (945.143 us; speedup 1.0000x reference)
//
#include <hip/hip_runtime.h>
#include <hip/hip_bf16.h>
#include <math.h>

typedef __attribute__((ext_vector_type(8))) short bf16x8;
typedef __attribute__((ext_vector_type(4))) short short4v;
typedef __attribute__((ext_vector_type(4))) float f32x4;
typedef __attribute__((ext_vector_type(16))) float f32x16;

#define MFMA16(a,b,c) __builtin_amdgcn_mfma_f32_16x16x32_bf16(a,b,c,0,0,0)
#define MFMA32(a,b,c) __builtin_amdgcn_mfma_f32_32x32x16_bf16(a,b,c,0,0,0)

__device__ __forceinline__ unsigned short f2bf(float f) {
  union { float f; unsigned u; } v; v.f = f;
  unsigned r = v.u + 0x7FFFu + ((v.u >> 16) & 1u);
  return (unsigned short)(r >> 16);
}
__device__ __forceinline__ float b2f(unsigned short u) {
  union { unsigned u; float f; } v; v.u = (unsigned)u << 16; return v.f;
}

__device__ __forceinline__ unsigned cvt_pk(float lo, float hi) {
  unsigned r;
  asm("v_cvt_pk_bf16_f32 %0, %1, %2" : "=v"(r) : "v"(lo), "v"(hi));
  return r;
}
__device__ __forceinline__ float fexp2(float x) {
  float r;
  asm("v_exp_f32 %0, %1" : "=v"(r) : "v"(x));
  return r;
}

__device__ __forceinline__ void async_load16(const void* g, void* lds) {
  __builtin_amdgcn_global_load_lds(
      (const __attribute__((address_space(1))) unsigned int*)g,
      (__attribute__((address_space(3))) unsigned int*)lds, 16, 0, 0);
}

__device__ __forceinline__ f32x16 zero16() {
  f32x16 z;
#pragma unroll
  for (int i = 0; i < 16; ++i) z[i] = 0.f;
  return z;
}

// ---------------- RoPE table ----------------
__global__ void rope_table_kernel(float* __restrict__ tc, float* __restrict__ ts) {
  int i = blockIdx.x * 256 + threadIdx.x;
  if (i >= 2048 * 32) return;
  int s = i >> 5, j = i & 31;
  double invf = pow(10000.0, -(double)(2 * j) / 64.0);
  double ang = (double)s * invf;
  tc[i] = (float)cos(ang);
  ts[i] = (float)sin(ang);
}

// ---------------- fp32 -> bf16 elementwise ----------------
__global__ __launch_bounds__(256) void cvt_kernel(const float* __restrict__ in,
                                                  unsigned short* __restrict__ out, int n4) {
  int i = blockIdx.x * 256 + threadIdx.x;
  if (i >= n4) return;
  float4 v = ((const float4*)in)[i];
  short4v o;
  o[0] = (short)f2bf(v.x); o[1] = (short)f2bf(v.y);
  o[2] = (short)f2bf(v.z); o[3] = (short)f2bf(v.w);
  *(short4v*)&out[(size_t)i * 4] = o;
}

// ---------------- fp32 [R][C] -> bf16 [C][R] transpose ----------------
__global__ __launch_bounds__(256) void transpose_cvt(const float* __restrict__ in,
                                                     unsigned short* __restrict__ out,
                                                     int R, int C) {
  __shared__ float tile[32][33];
  const int bx = blockIdx.x * 32, by = blockIdx.y * 32;
  const int tx = threadIdx.x & 31, ty0 = threadIdx.x >> 5;
#pragma unroll
  for (int p = 0; p < 4; ++p) {
    int r = ty0 + p * 8;
    tile[r][tx] = in[(size_t)(by + r) * C + bx + tx];
  }
  __syncthreads();
#pragma unroll
  for (int p = 0; p < 4; ++p) {
    int r = ty0 + p * 8;
    out[(size_t)(bx + r) * R + by + tx] = f2bf(tile[tx][r]);
  }
}

// ---------------- GEMM (m97 structure); BF16OUT selects output dtype ----------
template<bool BF16OUT>
__global__ __launch_bounds__(256) void gemm_bt(const unsigned short* __restrict__ A,
                                               const unsigned short* __restrict__ Bt,
                                               void* __restrict__ Cv,
                                               int M, int N, int K) {
  __shared__ unsigned short As[128 * 32];
  __shared__ unsigned short Bs[128 * 32];
  const int t = threadIdx.x, lane = t & 63, wv = t >> 6;
  const int bn = blockIdx.x, bm = blockIdx.y;
  const int m0 = bm * 128, n0 = bn * 128;
  f32x4 acc[4][4];
#pragma unroll
  for (int m = 0; m < 4; ++m)
#pragma unroll
    for (int n = 0; n < 4; ++n) acc[m][n] = (f32x4){0.f, 0.f, 0.f, 0.f};
  const int wr = (wv >> 1) * 64, wc = (wv & 1) * 64;
  const int ar = lane & 15, ak = (lane >> 4) * 8;
  const int srow = lane >> 2, skc = (lane & 3) * 8;
  const int nkt = K >> 5;
  for (int kt = 0; kt < nkt; ++kt) {
    const unsigned short* Ag = A + (size_t)m0 * K + kt * 32;
    const unsigned short* Bg = Bt + (size_t)n0 * K + kt * 32;
#pragma unroll
    for (int p = 0; p < 2; ++p) {
      int c = wv * 2 + p;
      async_load16(Ag + (size_t)(c * 16 + srow) * K + skc, &As[c * 512]);
      async_load16(Bg + (size_t)(c * 16 + srow) * K + skc, &Bs[c * 512]);
    }
    __syncthreads();
    bf16x8 af[4], bfr[4];
#pragma unroll
    for (int m = 0; m < 4; ++m) af[m] = *(const bf16x8*)&As[(wr + m * 16 + ar) * 32 + ak];
#pragma unroll
    for (int n = 0; n < 4; ++n) bfr[n] = *(const bf16x8*)&Bs[(wc + n * 16 + ar) * 32 + ak];
#pragma unroll
    for (int m = 0; m < 4; ++m)
#pragma unroll
      for (int n = 0; n < 4; ++n) acc[m][n] = MFMA16(af[m], bfr[n], acc[m][n]);
    __syncthreads();
  }
#pragma unroll
  for (int m = 0; m < 4; ++m) {
    int row = m0 + wr + m * 16 + (lane >> 4) * 4;
#pragma unroll
    for (int n = 0; n < 4; ++n) {
      int col = n0 + wc + n * 16 + ar;
      if (BF16OUT) {
        unsigned short* cp = (unsigned short*)Cv + (size_t)row * N + col;
#pragma unroll
        for (int j = 0; j < 4; ++j) cp[(size_t)j * N] = f2bf(acc[m][n][j]);
      } else {
        float* cp = (float*)Cv + (size_t)row * N + col;
#pragma unroll
        for (int j = 0; j < 4; ++j) cp[(size_t)j * N] = acc[m][n][j];
      }
    }
  }
}

// ---------------- RoPE apply + head split + V transpose (bf16 qkv in) -------
// Q gets 0.125 * log2(e) prescale (softmax runs in exp2 domain).
__global__ __launch_bounds__(256) void rope_kernel(const unsigned short* __restrict__ qkv,
                                                   const float* __restrict__ tc,
                                                   const float* __restrict__ ts,
                                                   unsigned short* __restrict__ qo,
                                                   unsigned short* __restrict__ ko,
                                                   unsigned short* __restrict__ vt) {
  const int S = 2048;
  const int bx = blockIdx.x;
  const int st = bx & 31, bh = bx >> 5;
  const int b = bh >> 4, h = bh & 15;
  const int t = threadIdx.x;
  const int sl = t >> 2, j0 = (t & 3) * 8;
  const int s = st * 64 + sl;
  const unsigned short* row = qkv + (size_t)(b * S + s) * 3072;
  float cv[8], sv[8];
#pragma unroll
  for (int i = 0; i < 8; ++i) {
    cv[i] = tc[s * 32 + j0 + i];
    sv[i] = ts[s * 32 + j0 + i];
  }
  __shared__ unsigned short vtile[64][66];
#pragma unroll
  for (int m = 0; m < 2; ++m) {
    const int col0 = m * 1024 + h * 64;
    const float qscale = (m == 0) ? 0.125f * 1.44269504088896340736f : 1.0f;
    bf16x8 lo8 = *(const bf16x8*)&row[col0 + j0];
    bf16x8 hi8 = *(const bf16x8*)&row[col0 + 32 + j0];
    bf16x8 outlo, outhi;
#pragma unroll
    for (int i = 0; i < 8; ++i) {
      float lo = b2f((unsigned short)lo8[i]), hi = b2f((unsigned short)hi8[i]);
      outlo[i] = (short)f2bf((lo * cv[i] - hi * sv[i]) * qscale);
      outhi[i] = (short)f2bf((hi * cv[i] + lo * sv[i]) * qscale);
    }
    unsigned short* dst = (m == 0 ? qo : ko) + (size_t)(bh * S + s) * 64;
    *(bf16x8*)&dst[j0] = outlo;
    *(bf16x8*)&dst[32 + j0] = outhi;
  }
  {
    const int col0 = 2048 + h * 64;
    bf16x8 v8a = *(const bf16x8*)&row[col0 + j0];
    bf16x8 v8b = *(const bf16x8*)&row[col0 + 32 + j0];
#pragma unroll
    for (int i = 0; i < 8; ++i) {
      vtile[j0 + i][sl] = (unsigned short)v8a[i];
      vtile[j0 + 32 + i][sl] = (unsigned short)v8b[i];
    }
  }
  __syncthreads();
  {
    const int hd = t >> 2, sc0 = (t & 3) * 16;
    unsigned short* dst = vt + ((size_t)bh * 64 + hd) * S + st * 64 + sc0;
    bf16x8 a, bv;
#pragma unroll
    for (int i = 0; i < 8; ++i) {
      a[i] = (short)vtile[hd][sc0 + i];
      bv[i] = (short)vtile[hd][sc0 + 8 + i];
    }
    *(bf16x8*)&dst[0] = a;
    *(bf16x8*)&dst[8] = bv;
  }
}

// ---------------- attention: split-K over keys, 8 waves/SIMD ----------------
// Each q-chain (32 rows, g+1 tiles) is split over keys into halves h0/h1,
// each owned by one wave (R8-proven 32-key tile body, VGPR~60 <= 64 ->
// 8 waves/SIMD). Partials (m,l,acc) merge in LDS via online-softmax rule.

__device__ __forceinline__ bf16x8 buildP(const unsigned* w, int tt, int hi) {
  const int base = (tt & 1) * 4 + (tt >> 1) * 8;
  unsigned wA = w[base], wB = w[base + 1], wC = w[base + 2], wD = w[base + 3];
  unsigned s1v = __shfl_xor(hi ? wA : wC, 32);
  unsigned s2v = __shfl_xor(hi ? wB : wD, 32);
  union { unsigned u[4]; bf16x8 v; } pw;
  pw.u[0] = hi ? s1v : wA;
  pw.u[1] = hi ? s2v : wB;
  pw.u[2] = hi ? wC : s1v;
  pw.u[3] = hi ? wD : s2v;
  return pw.v;
}

template<bool MASK>
__device__ __forceinline__ void tile32(
    const unsigned short* __restrict__ krow,
    const unsigned short* __restrict__ vr0, const unsigned short* __restrict__ vr1,
    int ql, int hi, const bf16x8 (&qf)[4],
    f32x16& a0, f32x16& a1, float& m_run, float& l_run) {
  bf16x8 k0[4];
#pragma unroll
  for (int s = 0; s < 4; ++s) k0[s] = *(const bf16x8*)&krow[s * 16];
  bf16x8 v0[2], v1[2];
  v0[0] = *(const bf16x8*)&vr0[0];
  v0[1] = *(const bf16x8*)&vr0[16];
  v1[0] = *(const bf16x8*)&vr1[0];
  v1[1] = *(const bf16x8*)&vr1[16];

  f32x16 s0 = zero16();
  __builtin_amdgcn_s_setprio(1);
#pragma unroll
  for (int s = 0; s < 4; ++s) s0 = MFMA32(k0[s], qf[s], s0);
  __builtin_amdgcn_s_setprio(0);

  if (MASK) {
#pragma unroll
    for (int r = 0; r < 16; ++r) {
      const int key = (r & 3) + 8 * (r >> 2) + 4 * hi;
      if (key > ql) s0[r] = -INFINITY;
    }
  }

  float p[8];
#pragma unroll
  for (int i = 0; i < 8; ++i) p[i] = fmaxf(s0[2 * i], s0[2 * i + 1]);
#pragma unroll
  for (int i = 0; i < 4; ++i) p[i] = fmaxf(p[i], p[i + 4]);
  float mx = fmaxf(fmaxf(p[0], p[1]), fmaxf(p[2], p[3]));
  mx = fmaxf(mx, __shfl_xor(mx, 32));
  const bool defer = __all(mx - m_run <= 8.0f) != 0;
  const float mn = defer ? m_run : fmaxf(m_run, mx);
  float r0 = 0.f, r1 = 0.f, r2 = 0.f, r3 = 0.f;
#pragma unroll
  for (int i = 0; i < 4; ++i) {
    float e0 = fexp2(s0[4 * i + 0] - mn); s0[4 * i + 0] = e0; r0 += e0;
    float e1 = fexp2(s0[4 * i + 1] - mn); s0[4 * i + 1] = e1; r1 += e1;
    float e2 = fexp2(s0[4 * i + 2] - mn); s0[4 * i + 2] = e2; r2 += e2;
    float e3 = fexp2(s0[4 * i + 3] - mn); s0[4 * i + 3] = e3; r3 += e3;
  }
  const float rs = (r0 + r1) + (r2 + r3);
  if (defer) {
    l_run += rs;
  } else {
    const float scl = fexp2(m_run - mn);
    m_run = mn;
    l_run = l_run * scl + rs;
#pragma unroll
    for (int r = 0; r < 16; ++r) { a0[r] *= scl; a1[r] *= scl; }
  }
  unsigned w[8];
#pragma unroll
  for (int i = 0; i < 8; ++i) w[i] = cvt_pk(s0[2 * i], s0[2 * i + 1]);

  __builtin_amdgcn_s_setprio(1);
#pragma unroll
  for (int tt = 0; tt < 2; ++tt) {
    bf16x8 pp = buildP(w, tt, hi);
    a0 = MFMA32(v0[tt], pp, a0);
    a1 = MFMA32(v1[tt], pp, a1);
  }
  __builtin_amdgcn_s_setprio(0);
}

// grid: 2048 blocks (XCD-swizzled: 8 chunks of 256). Block (bh, j):
// chains X=j, Y=63-j; pieces {Xh0,Xh1,Yh0,Yh1} assigned to waves by
// rotation (wv+j)&3 for SIMD load balance. h1 partials stored in LDS;
// h0 waves merge and write output.
__global__ __launch_bounds__(256, 8) void attn_kernel(const unsigned short* __restrict__ Q,
                                                      const unsigned short* __restrict__ Kk,
                                                      const unsigned short* __restrict__ Vt,
                                                      unsigned short* __restrict__ O) {
  const int S = 2048;
  const int t = threadIdx.x, lane = t & 63, wv = t >> 6;
  const int swz = (blockIdx.x & 7) * 256 + (blockIdx.x >> 3);
  const int bh = swz >> 5, j = swz & 31;
  const int b = bh >> 4, h = bh & 15;
  const int piece = (wv + j) & 3;              // 0=Xh0 1=Xh1 2=Yh0 3=Yh1
  const int g = (piece < 2) ? j : 63 - j;
  const int T = g + 1;
  const int Th0 = (T + 1) >> 1;
  const bool isH1 = (piece & 1) != 0;
  const int tStart = isH1 ? Th0 : 0;
  const int tCount = isH1 ? T - Th0 : Th0;
  const bool hasDiag = (tCount > 0) && (tStart + tCount == T);
  const int nFull = hasDiag ? tCount - 1 : tCount;
  const int ql = lane & 31, hi = lane >> 5;
  const unsigned short* qh = Q + (size_t)bh * S * 64;
  const unsigned short* kh = Kk + (size_t)bh * S * 64;
  const unsigned short* vh = Vt + (size_t)bh * 64 * S;

  bf16x8 qf[4];
#pragma unroll
  for (int s = 0; s < 4; ++s)
    qf[s] = *(const bf16x8*)&qh[(size_t)(32 * g + ql) * 64 + s * 16 + hi * 8];

  f32x16 a0 = zero16(), a1 = zero16();
  float m_run = -INFINITY, l_run = 0.f;

  const unsigned short* krow = kh + ql * 64 + hi * 8 + (size_t)tStart * 2048;
  const unsigned short* vr0 = vh + (size_t)ql * S + hi * 8 + tStart * 32;
  const unsigned short* vr1 = vh + (size_t)(32 + ql) * S + hi * 8 + tStart * 32;

  for (int kt = 0; kt < nFull; ++kt) {
    tile32<false>(krow, vr0, vr1, ql, hi, qf, a0, a1, m_run, l_run);
    krow += 2048;
    vr0 += 32;
    vr1 += 32;
  }
  if (hasDiag)
    tile32<true>(krow, vr0, vr1, ql, hi, qf, a0, a1, m_run, l_run);

  // ---- split-K merge: h1 partials -> LDS; h0 waves combine + write ----
  __shared__ float part[2][64][34];  // [slot][lane][32 acc, l, m]
  if (isH1) {
    const int slot = piece >> 1;
#pragma unroll
    for (int r = 0; r < 16; ++r) {
      part[slot][lane][r] = a0[r];
      part[slot][lane][16 + r] = a1[r];
    }
    part[slot][lane][32] = l_run;
    part[slot][lane][33] = m_run;
  }
  __syncthreads();
  if (!isH1) {
    const int slot = piece >> 1;
    const float mB = part[slot][lane][33];
    const float lB = part[slot][lane][32];
    const float M = fmaxf(m_run, mB);
    const float sA = fexp2(m_run - M);
    const float sB = fexp2(mB - M);   // exp2(-inf)=0 handles empty h1
    float l = l_run * sA + lB * sB;
    l += __shfl_xor(l, 32);
    const float inv = 1.f / l;
    unsigned short* orow = O + (size_t)(b * S + 32 * g + ql) * 1024 + h * 64;
#pragma unroll
    for (int r = 0; r < 16; ++r) {
      int d = (r & 3) + 8 * (r >> 2) + 4 * hi;
      orow[d] = f2bf((a0[r] * sA + part[slot][lane][r] * sB) * inv);
      orow[32 + d] = f2bf((a1[r] * sA + part[slot][lane][16 + r] * sB) * inv);
    }
  }
}

extern "C" void kernel_launch(void* const* d_in, const int* in_sizes, int n_in,
                              void* d_out, int out_size, void* d_ws, size_t ws_size,
                              hipStream_t stream) {
  const float* x = (const float*)d_in[0];
  const float* Wqkv = (const float*)d_in[1];
  const float* Wout = (const float*)d_in[2];
  float* out = (float*)d_out;

  char* ws = (char*)d_ws;
  size_t off = 0;
  auto take = [&](size_t bytes) {
    void* p = ws + off;
    off += (bytes + 255) & ~(size_t)255;
    return p;
  };
  float* tc = (float*)take(2048 * 32 * 4);
  float* tsn = (float*)take(2048 * 32 * 4);
  unsigned short* xbf = (unsigned short*)take((size_t)8192 * 1024 * 2);
  unsigned short* wqkvT = (unsigned short*)take((size_t)3072 * 1024 * 2);
  unsigned short* woutT = (unsigned short*)take((size_t)1024 * 1024 * 2);
  unsigned short* qkvb = (unsigned short*)take((size_t)8192 * 3072 * 2);
  unsigned short* qb_ = (unsigned short*)take((size_t)64 * 2048 * 64 * 2);
  unsigned short* kb_ = (unsigned short*)take((size_t)64 * 2048 * 64 * 2);
  unsigned short* vt = (unsigned short*)take((size_t)64 * 64 * 2048 * 2);
  unsigned short* attn = (unsigned short*)take((size_t)8192 * 1024 * 2);

  rope_table_kernel<<<256, 256, 0, stream>>>(tc, tsn);
  cvt_kernel<<<(2097152 + 255) / 256, 256, 0, stream>>>(x, xbf, 2097152);
  {
    dim3 g(96, 32);
    transpose_cvt<<<g, 256, 0, stream>>>(Wqkv, wqkvT, 1024, 3072);
  }
  {
    dim3 g(32, 32);
    transpose_cvt<<<g, 256, 0, stream>>>(Wout, woutT, 1024, 1024);
  }
  {
    dim3 g(24, 64);
    gemm_bt<true><<<g, 256, 0, stream>>>(xbf, wqkvT, qkvb, 8192, 3072, 1024);
  }
  rope_kernel<<<2048, 256, 0, stream>>>(qkvb, tc, tsn, qb_, kb_, vt);
  attn_kernel<<<2048, 256, 0, stream>>>(qb_, kb_, vt, attn);
  {
    dim3 g(8, 64);
    gemm_bt<false><<<g, 256, 0, stream>>>(attn, woutT, out, 8192, 1024, 1024);
  }
}

// Round 15
// 268.127 us; speedup vs baseline: 3.5250x; 3.5250x over previous
//
#include <hip/hip_runtime.h>
#include <hip/hip_bf16.h>
#include <math.h>

typedef __attribute__((ext_vector_type(8))) short bf16x8;
typedef __attribute__((ext_vector_type(4))) short short4v;
typedef __attribute__((ext_vector_type(4))) float f32x4;
typedef __attribute__((ext_vector_type(16))) float f32x16;

#define MFMA16(a,b,c) __builtin_amdgcn_mfma_f32_16x16x32_bf16(a,b,c,0,0,0)
#define MFMA32(a,b,c) __builtin_amdgcn_mfma_f32_32x32x16_bf16(a,b,c,0,0,0)

__device__ __forceinline__ unsigned short f2bf(float f) {
  union { float f; unsigned u; } v; v.f = f;
  unsigned r = v.u + 0x7FFFu + ((v.u >> 16) & 1u);
  return (unsigned short)(r >> 16);
}
__device__ __forceinline__ float b2f(unsigned short u) {
  union { unsigned u; float f; } v; v.u = (unsigned)u << 16; return v.f;
}

__device__ __forceinline__ unsigned cvt_pk(float lo, float hi) {
  unsigned r;
  asm("v_cvt_pk_bf16_f32 %0, %1, %2" : "=v"(r) : "v"(lo), "v"(hi));
  return r;
}
__device__ __forceinline__ float fexp2(float x) {
  float r;
  asm("v_exp_f32 %0, %1" : "=v"(r) : "v"(x));
  return r;
}

__device__ __forceinline__ void async_load16(const void* g, void* lds) {
  __builtin_amdgcn_global_load_lds(
      (const __attribute__((address_space(1))) unsigned int*)g,
      (__attribute__((address_space(3))) unsigned int*)lds, 16, 0, 0);
}

__device__ __forceinline__ f32x16 zero16() {
  f32x16 z;
#pragma unroll
  for (int i = 0; i < 16; ++i) z[i] = 0.f;
  return z;
}

// ---------------- RoPE table ----------------
__global__ void rope_table_kernel(float* __restrict__ tc, float* __restrict__ ts) {
  int i = blockIdx.x * 256 + threadIdx.x;
  if (i >= 2048 * 32) return;
  int s = i >> 5, j = i & 31;
  double invf = pow(10000.0, -(double)(2 * j) / 64.0);
  double ang = (double)s * invf;
  tc[i] = (float)cos(ang);
  ts[i] = (float)sin(ang);
}

// ---------------- fp32 -> bf16 elementwise ----------------
__global__ __launch_bounds__(256) void cvt_kernel(const float* __restrict__ in,
                                                  unsigned short* __restrict__ out, int n4) {
  int i = blockIdx.x * 256 + threadIdx.x;
  if (i >= n4) return;
  float4 v = ((const float4*)in)[i];
  short4v o;
  o[0] = (short)f2bf(v.x); o[1] = (short)f2bf(v.y);
  o[2] = (short)f2bf(v.z); o[3] = (short)f2bf(v.w);
  *(short4v*)&out[(size_t)i * 4] = o;
}

// ---------------- fp32 [R][C] -> bf16 [C][R] transpose ----------------
__global__ __launch_bounds__(256) void transpose_cvt(const float* __restrict__ in,
                                                     unsigned short* __restrict__ out,
                                                     int R, int C) {
  __shared__ float tile[32][33];
  const int bx = blockIdx.x * 32, by = blockIdx.y * 32;
  const int tx = threadIdx.x & 31, ty0 = threadIdx.x >> 5;
#pragma unroll
  for (int p = 0; p < 4; ++p) {
    int r = ty0 + p * 8;
    tile[r][tx] = in[(size_t)(by + r) * C + bx + tx];
  }
  __syncthreads();
#pragma unroll
  for (int p = 0; p < 4; ++p) {
    int r = ty0 + p * 8;
    out[(size_t)(bx + r) * R + by + tx] = f2bf(tile[tx][r]);
  }
}

// ---------------- GEMM (m97 structure); BF16OUT selects output dtype ----------
template<bool BF16OUT>
__global__ __launch_bounds__(256) void gemm_bt(const unsigned short* __restrict__ A,
                                               const unsigned short* __restrict__ Bt,
                                               void* __restrict__ Cv,
                                               int M, int N, int K) {
  __shared__ unsigned short As[128 * 32];
  __shared__ unsigned short Bs[128 * 32];
  const int t = threadIdx.x, lane = t & 63, wv = t >> 6;
  const int bn = blockIdx.x, bm = blockIdx.y;
  const int m0 = bm * 128, n0 = bn * 128;
  f32x4 acc[4][4];
#pragma unroll
  for (int m = 0; m < 4; ++m)
#pragma unroll
    for (int n = 0; n < 4; ++n) acc[m][n] = (f32x4){0.f, 0.f, 0.f, 0.f};
  const int wr = (wv >> 1) * 64, wc = (wv & 1) * 64;
  const int ar = lane & 15, ak = (lane >> 4) * 8;
  const int srow = lane >> 2, skc = (lane & 3) * 8;
  const int nkt = K >> 5;
  for (int kt = 0; kt < nkt; ++kt) {
    const unsigned short* Ag = A + (size_t)m0 * K + kt * 32;
    const unsigned short* Bg = Bt + (size_t)n0 * K + kt * 32;
#pragma unroll
    for (int p = 0; p < 2; ++p) {
      int c = wv * 2 + p;
      async_load16(Ag + (size_t)(c * 16 + srow) * K + skc, &As[c * 512]);
      async_load16(Bg + (size_t)(c * 16 + srow) * K + skc, &Bs[c * 512]);
    }
    __syncthreads();
    bf16x8 af[4], bfr[4];
#pragma unroll
    for (int m = 0; m < 4; ++m) af[m] = *(const bf16x8*)&As[(wr + m * 16 + ar) * 32 + ak];
#pragma unroll
    for (int n = 0; n < 4; ++n) bfr[n] = *(const bf16x8*)&Bs[(wc + n * 16 + ar) * 32 + ak];
#pragma unroll
    for (int m = 0; m < 4; ++m)
#pragma unroll
      for (int n = 0; n < 4; ++n) acc[m][n] = MFMA16(af[m], bfr[n], acc[m][n]);
    __syncthreads();
  }
#pragma unroll
  for (int m = 0; m < 4; ++m) {
    int row = m0 + wr + m * 16 + (lane >> 4) * 4;
#pragma unroll
    for (int n = 0; n < 4; ++n) {
      int col = n0 + wc + n * 16 + ar;
      if (BF16OUT) {
        unsigned short* cp = (unsigned short*)Cv + (size_t)row * N + col;
#pragma unroll
        for (int j = 0; j < 4; ++j) cp[(size_t)j * N] = f2bf(acc[m][n][j]);
      } else {
        float* cp = (float*)Cv + (size_t)row * N + col;
#pragma unroll
        for (int j = 0; j < 4; ++j) cp[(size_t)j * N] = acc[m][n][j];
      }
    }
  }
}

// ---------------- RoPE apply + head split + V transpose (bf16 qkv in) -------
// Q gets 0.125 * log2(e) prescale (softmax runs in exp2 domain).
__global__ __launch_bounds__(256) void rope_kernel(const unsigned short* __restrict__ qkv,
                                                   const float* __restrict__ tc,
                                                   const float* __restrict__ ts,
                                                   unsigned short* __restrict__ qo,
                                                   unsigned short* __restrict__ ko,
                                                   unsigned short* __restrict__ vt) {
  const int S = 2048;
  const int bx = blockIdx.x;
  const int st = bx & 31, bh = bx >> 5;
  const int b = bh >> 4, h = bh & 15;
  const int t = threadIdx.x;
  const int sl = t >> 2, j0 = (t & 3) * 8;
  const int s = st * 64 + sl;
  const unsigned short* row = qkv + (size_t)(b * S + s) * 3072;
  float cv[8], sv[8];
#pragma unroll
  for (int i = 0; i < 8; ++i) {
    cv[i] = tc[s * 32 + j0 + i];
    sv[i] = ts[s * 32 + j0 + i];
  }
  __shared__ unsigned short vtile[64][66];
#pragma unroll
  for (int m = 0; m < 2; ++m) {
    const int col0 = m * 1024 + h * 64;
    const float qscale = (m == 0) ? 0.125f * 1.44269504088896340736f : 1.0f;
    bf16x8 lo8 = *(const bf16x8*)&row[col0 + j0];
    bf16x8 hi8 = *(const bf16x8*)&row[col0 + 32 + j0];
    bf16x8 outlo, outhi;
#pragma unroll
    for (int i = 0; i < 8; ++i) {
      float lo = b2f((unsigned short)lo8[i]), hi = b2f((unsigned short)hi8[i]);
      outlo[i] = (short)f2bf((lo * cv[i] - hi * sv[i]) * qscale);
      outhi[i] = (short)f2bf((hi * cv[i] + lo * sv[i]) * qscale);
    }
    unsigned short* dst = (m == 0 ? qo : ko) + (size_t)(bh * S + s) * 64;
    *(bf16x8*)&dst[j0] = outlo;
    *(bf16x8*)&dst[32 + j0] = outhi;
  }
  {
    const int col0 = 2048 + h * 64;
    bf16x8 v8a = *(const bf16x8*)&row[col0 + j0];
    bf16x8 v8b = *(const bf16x8*)&row[col0 + 32 + j0];
#pragma unroll
    for (int i = 0; i < 8; ++i) {
      vtile[j0 + i][sl] = (unsigned short)v8a[i];
      vtile[j0 + 32 + i][sl] = (unsigned short)v8b[i];
    }
  }
  __syncthreads();
  {
    const int hd = t >> 2, sc0 = (t & 3) * 16;
    unsigned short* dst = vt + ((size_t)bh * 64 + hd) * S + st * 64 + sc0;
    bf16x8 a, bv;
#pragma unroll
    for (int i = 0; i < 8; ++i) {
      a[i] = (short)vtile[hd][sc0 + i];
      bv[i] = (short)vtile[hd][sc0 + 8 + i];
    }
    *(bf16x8*)&dst[0] = a;
    *(bf16x8*)&dst[8] = bv;
  }
}

// ---------------- attention: split-K over keys, natural 8 waves/SIMD ----------
// R14 structure (validated correct) with launch_bounds(256,3): the allocator
// lands at ~60 VGPR for this body (proven R8/R9), and 60 <= 64 lets the HW run
// 8 blocks/CU from the 2048-block grid without any forced cap (R14's spill).

__device__ __forceinline__ bf16x8 buildP(const unsigned* w, int tt, int hi) {
  const int base = (tt & 1) * 4 + (tt >> 1) * 8;
  unsigned wA = w[base], wB = w[base + 1], wC = w[base + 2], wD = w[base + 3];
  unsigned s1v = __shfl_xor(hi ? wA : wC, 32);
  unsigned s2v = __shfl_xor(hi ? wB : wD, 32);
  union { unsigned u[4]; bf16x8 v; } pw;
  pw.u[0] = hi ? s1v : wA;
  pw.u[1] = hi ? s2v : wB;
  pw.u[2] = hi ? wC : s1v;
  pw.u[3] = hi ? wD : s2v;
  return pw.v;
}

template<bool MASK>
__device__ __forceinline__ void tile32(
    const unsigned short* __restrict__ krow,
    const unsigned short* __restrict__ vr0, const unsigned short* __restrict__ vr1,
    int ql, int hi, const bf16x8 (&qf)[4],
    f32x16& a0, f32x16& a1, float& m_run, float& l_run) {
  bf16x8 k0[4];
#pragma unroll
  for (int s = 0; s < 4; ++s) k0[s] = *(const bf16x8*)&krow[s * 16];
  bf16x8 v0[2], v1[2];
  v0[0] = *(const bf16x8*)&vr0[0];
  v0[1] = *(const bf16x8*)&vr0[16];
  v1[0] = *(const bf16x8*)&vr1[0];
  v1[1] = *(const bf16x8*)&vr1[16];

  f32x16 s0 = zero16();
  __builtin_amdgcn_s_setprio(1);
#pragma unroll
  for (int s = 0; s < 4; ++s) s0 = MFMA32(k0[s], qf[s], s0);
  __builtin_amdgcn_s_setprio(0);

  if (MASK) {
#pragma unroll
    for (int r = 0; r < 16; ++r) {
      const int key = (r & 3) + 8 * (r >> 2) + 4 * hi;
      if (key > ql) s0[r] = -INFINITY;
    }
  }

  float p[8];
#pragma unroll
  for (int i = 0; i < 8; ++i) p[i] = fmaxf(s0[2 * i], s0[2 * i + 1]);
#pragma unroll
  for (int i = 0; i < 4; ++i) p[i] = fmaxf(p[i], p[i + 4]);
  float mx = fmaxf(fmaxf(p[0], p[1]), fmaxf(p[2], p[3]));
  mx = fmaxf(mx, __shfl_xor(mx, 32));
  const bool defer = __all(mx - m_run <= 8.0f) != 0;
  const float mn = defer ? m_run : fmaxf(m_run, mx);
  float r0 = 0.f, r1 = 0.f, r2 = 0.f, r3 = 0.f;
#pragma unroll
  for (int i = 0; i < 4; ++i) {
    float e0 = fexp2(s0[4 * i + 0] - mn); s0[4 * i + 0] = e0; r0 += e0;
    float e1 = fexp2(s0[4 * i + 1] - mn); s0[4 * i + 1] = e1; r1 += e1;
    float e2 = fexp2(s0[4 * i + 2] - mn); s0[4 * i + 2] = e2; r2 += e2;
    float e3 = fexp2(s0[4 * i + 3] - mn); s0[4 * i + 3] = e3; r3 += e3;
  }
  const float rs = (r0 + r1) + (r2 + r3);
  if (defer) {
    l_run += rs;
  } else {
    const float scl = fexp2(m_run - mn);
    m_run = mn;
    l_run = l_run * scl + rs;
#pragma unroll
    for (int r = 0; r < 16; ++r) { a0[r] *= scl; a1[r] *= scl; }
  }
  unsigned w[8];
#pragma unroll
  for (int i = 0; i < 8; ++i) w[i] = cvt_pk(s0[2 * i], s0[2 * i + 1]);

  __builtin_amdgcn_s_setprio(1);
#pragma unroll
  for (int tt = 0; tt < 2; ++tt) {
    bf16x8 pp = buildP(w, tt, hi);
    a0 = MFMA32(v0[tt], pp, a0);
    a1 = MFMA32(v1[tt], pp, a1);
  }
  __builtin_amdgcn_s_setprio(0);
}

// grid: 2048 blocks (XCD-swizzled: 8 chunks of 256). Block (bh, j):
// chains X=j, Y=63-j; pieces {Xh0,Xh1,Yh0,Yh1} rotated by (wv+j)&3.
// h1 partials -> LDS; h0 waves merge (online-softmax rule) and write.
__global__ __launch_bounds__(256, 3) void attn_kernel(const unsigned short* __restrict__ Q,
                                                      const unsigned short* __restrict__ Kk,
                                                      const unsigned short* __restrict__ Vt,
                                                      unsigned short* __restrict__ O) {
  const int S = 2048;
  const int t = threadIdx.x, lane = t & 63, wv = t >> 6;
  const int swz = (blockIdx.x & 7) * 256 + (blockIdx.x >> 3);
  const int bh = swz >> 5, j = swz & 31;
  const int b = bh >> 4, h = bh & 15;
  const int piece = (wv + j) & 3;              // 0=Xh0 1=Xh1 2=Yh0 3=Yh1
  const int g = (piece < 2) ? j : 63 - j;
  const int T = g + 1;
  const int Th0 = (T + 1) >> 1;
  const bool isH1 = (piece & 1) != 0;
  const int tStart = isH1 ? Th0 : 0;
  const int tCount = isH1 ? T - Th0 : Th0;
  const bool hasDiag = (tCount > 0) && (tStart + tCount == T);
  const int nFull = hasDiag ? tCount - 1 : tCount;
  const int ql = lane & 31, hi = lane >> 5;
  const unsigned short* qh = Q + (size_t)bh * S * 64;
  const unsigned short* kh = Kk + (size_t)bh * S * 64;
  const unsigned short* vh = Vt + (size_t)bh * 64 * S;

  bf16x8 qf[4];
#pragma unroll
  for (int s = 0; s < 4; ++s)
    qf[s] = *(const bf16x8*)&qh[(size_t)(32 * g + ql) * 64 + s * 16 + hi * 8];

  f32x16 a0 = zero16(), a1 = zero16();
  float m_run = -INFINITY, l_run = 0.f;

  const unsigned short* krow = kh + ql * 64 + hi * 8 + (size_t)tStart * 2048;
  const unsigned short* vr0 = vh + (size_t)ql * S + hi * 8 + tStart * 32;
  const unsigned short* vr1 = vh + (size_t)(32 + ql) * S + hi * 8 + tStart * 32;

  for (int kt = 0; kt < nFull; ++kt) {
    tile32<false>(krow, vr0, vr1, ql, hi, qf, a0, a1, m_run, l_run);
    krow += 2048;
    vr0 += 32;
    vr1 += 32;
  }
  if (hasDiag)
    tile32<true>(krow, vr0, vr1, ql, hi, qf, a0, a1, m_run, l_run);

  // ---- split-K merge: h1 partials -> LDS; h0 waves combine + write ----
  __shared__ float part[2][64][34];  // [slot][lane][32 acc, l, m]
  if (isH1) {
    const int slot = piece >> 1;
#pragma unroll
    for (int r = 0; r < 16; ++r) {
      part[slot][lane][r] = a0[r];
      part[slot][lane][16 + r] = a1[r];
    }
    part[slot][lane][32] = l_run;
    part[slot][lane][33] = m_run;
  }
  __syncthreads();
  if (!isH1) {
    const int slot = piece >> 1;
    const float mB = part[slot][lane][33];
    const float lB = part[slot][lane][32];
    const float M = fmaxf(m_run, mB);
    const float sA = fexp2(m_run - M);
    const float sB = fexp2(mB - M);   // exp2(-inf)=0 handles empty h1
    float l = l_run * sA + lB * sB;
    l += __shfl_xor(l, 32);
    const float inv = 1.f / l;
    unsigned short* orow = O + (size_t)(b * S + 32 * g + ql) * 1024 + h * 64;
#pragma unroll
    for (int r = 0; r < 16; ++r) {
      int d = (r & 3) + 8 * (r >> 2) + 4 * hi;
      orow[d] = f2bf((a0[r] * sA + part[slot][lane][r] * sB) * inv);
      orow[32 + d] = f2bf((a1[r] * sA + part[slot][lane][16 + r] * sB) * inv);
    }
  }
}

extern "C" void kernel_launch(void* const* d_in, const int* in_sizes, int n_in,
                              void* d_out, int out_size, void* d_ws, size_t ws_size,
                              hipStream_t stream) {
  const float* x = (const float*)d_in[0];
  const float* Wqkv = (const float*)d_in[1];
  const float* Wout = (const float*)d_in[2];
  float* out = (float*)d_out;

  char* ws = (char*)d_ws;
  size_t off = 0;
  auto take = [&](size_t bytes) {
    void* p = ws + off;
    off += (bytes + 255) & ~(size_t)255;
    return p;
  };
  float* tc = (float*)take(2048 * 32 * 4);
  float* tsn = (float*)take(2048 * 32 * 4);
  unsigned short* xbf = (unsigned short*)take((size_t)8192 * 1024 * 2);
  unsigned short* wqkvT = (unsigned short*)take((size_t)3072 * 1024 * 2);
  unsigned short* woutT = (unsigned short*)take((size_t)1024 * 1024 * 2);
  unsigned short* qkvb = (unsigned short*)take((size_t)8192 * 3072 * 2);
  unsigned short* qb_ = (unsigned short*)take((size_t)64 * 2048 * 64 * 2);
  unsigned short* kb_ = (unsigned short*)take((size_t)64 * 2048 * 64 * 2);
  unsigned short* vt = (unsigned short*)take((size_t)64 * 64 * 2048 * 2);
  unsigned short* attn = (unsigned short*)take((size_t)8192 * 1024 * 2);

  rope_table_kernel<<<256, 256, 0, stream>>>(tc, tsn);
  cvt_kernel<<<(2097152 + 255) / 256, 256, 0, stream>>>(x, xbf, 2097152);
  {
    dim3 g(96, 32);
    transpose_cvt<<<g, 256, 0, stream>>>(Wqkv, wqkvT, 1024, 3072);
  }
  {
    dim3 g(32, 32);
    transpose_cvt<<<g, 256, 0, stream>>>(Wout, woutT, 1024, 1024);
  }
  {
    dim3 g(24, 64);
    gemm_bt<true><<<g, 256, 0, stream>>>(xbf, wqkvT, qkvb, 8192, 3072, 1024);
  }
  rope_kernel<<<2048, 256, 0, stream>>>(qkvb, tc, tsn, qb_, kb_, vt);
  attn_kernel<<<2048, 256, 0, stream>>>(qb_, kb_, vt, attn);
  {
    dim3 g(8, 64);
    gemm_bt<false><<<g, 256, 0, stream>>>(attn, woutT, out, 8192, 1024, 1024);
  }
}

// Round 16
// 222.535 us; speedup vs baseline: 4.2472x; 1.2049x over previous
//
#include <hip/hip_runtime.h>
#include <hip/hip_bf16.h>
#include <math.h>

typedef __attribute__((ext_vector_type(8))) short bf16x8;
typedef __attribute__((ext_vector_type(4))) short short4v;
typedef __attribute__((ext_vector_type(4))) float f32x4;
typedef __attribute__((ext_vector_type(16))) float f32x16;

#define MFMA16(a,b,c) __builtin_amdgcn_mfma_f32_16x16x32_bf16(a,b,c,0,0,0)
#define MFMA32(a,b,c) __builtin_amdgcn_mfma_f32_32x32x16_bf16(a,b,c,0,0,0)

__device__ __forceinline__ unsigned short f2bf(float f) {
  union { float f; unsigned u; } v; v.f = f;
  unsigned r = v.u + 0x7FFFu + ((v.u >> 16) & 1u);
  return (unsigned short)(r >> 16);
}
__device__ __forceinline__ float b2f(unsigned short u) {
  union { unsigned u; float f; } v; v.u = (unsigned)u << 16; return v.f;
}

__device__ __forceinline__ unsigned cvt_pk(float lo, float hi) {
  unsigned r;
  asm("v_cvt_pk_bf16_f32 %0, %1, %2" : "=v"(r) : "v"(lo), "v"(hi));
  return r;
}
__device__ __forceinline__ float fexp2(float x) {
  float r;
  asm("v_exp_f32 %0, %1" : "=v"(r) : "v"(x));
  return r;
}

__device__ __forceinline__ void async_load16(const void* g, void* lds) {
  __builtin_amdgcn_global_load_lds(
      (const __attribute__((address_space(1))) unsigned int*)g,
      (__attribute__((address_space(3))) unsigned int*)lds, 16, 0, 0);
}

__device__ __forceinline__ f32x16 zero16() {
  f32x16 z;
#pragma unroll
  for (int i = 0; i < 16; ++i) z[i] = 0.f;
  return z;
}

// ---------------- RoPE table ----------------
__global__ void rope_table_kernel(float* __restrict__ tc, float* __restrict__ ts) {
  int i = blockIdx.x * 256 + threadIdx.x;
  if (i >= 2048 * 32) return;
  int s = i >> 5, j = i & 31;
  double invf = pow(10000.0, -(double)(2 * j) / 64.0);
  double ang = (double)s * invf;
  tc[i] = (float)cos(ang);
  ts[i] = (float)sin(ang);
}

// ---------------- fp32 -> bf16 elementwise ----------------
__global__ __launch_bounds__(256) void cvt_kernel(const float* __restrict__ in,
                                                  unsigned short* __restrict__ out, int n4) {
  int i = blockIdx.x * 256 + threadIdx.x;
  if (i >= n4) return;
  float4 v = ((const float4*)in)[i];
  short4v o;
  o[0] = (short)f2bf(v.x); o[1] = (short)f2bf(v.y);
  o[2] = (short)f2bf(v.z); o[3] = (short)f2bf(v.w);
  *(short4v*)&out[(size_t)i * 4] = o;
}

// ---------------- fp32 [R][C] -> bf16 [C][R] transpose ----------------
__global__ __launch_bounds__(256) void transpose_cvt(const float* __restrict__ in,
                                                     unsigned short* __restrict__ out,
                                                     int R, int C) {
  __shared__ float tile[32][33];
  const int bx = blockIdx.x * 32, by = blockIdx.y * 32;
  const int tx = threadIdx.x & 31, ty0 = threadIdx.x >> 5;
#pragma unroll
  for (int p = 0; p < 4; ++p) {
    int r = ty0 + p * 8;
    tile[r][tx] = in[(size_t)(by + r) * C + bx + tx];
  }
  __syncthreads();
#pragma unroll
  for (int p = 0; p < 4; ++p) {
    int r = ty0 + p * 8;
    out[(size_t)(bx + r) * R + by + tx] = f2bf(tile[tx][r]);
  }
}

// ---------------- GEMM (m97 structure); BF16OUT selects output dtype ----------
template<bool BF16OUT>
__global__ __launch_bounds__(256) void gemm_bt(const unsigned short* __restrict__ A,
                                               const unsigned short* __restrict__ Bt,
                                               void* __restrict__ Cv,
                                               int M, int N, int K) {
  __shared__ unsigned short As[128 * 32];
  __shared__ unsigned short Bs[128 * 32];
  const int t = threadIdx.x, lane = t & 63, wv = t >> 6;
  const int bn = blockIdx.x, bm = blockIdx.y;
  const int m0 = bm * 128, n0 = bn * 128;
  f32x4 acc[4][4];
#pragma unroll
  for (int m = 0; m < 4; ++m)
#pragma unroll
    for (int n = 0; n < 4; ++n) acc[m][n] = (f32x4){0.f, 0.f, 0.f, 0.f};
  const int wr = (wv >> 1) * 64, wc = (wv & 1) * 64;
  const int ar = lane & 15, ak = (lane >> 4) * 8;
  const int srow = lane >> 2, skc = (lane & 3) * 8;
  const int nkt = K >> 5;
  for (int kt = 0; kt < nkt; ++kt) {
    const unsigned short* Ag = A + (size_t)m0 * K + kt * 32;
    const unsigned short* Bg = Bt + (size_t)n0 * K + kt * 32;
#pragma unroll
    for (int p = 0; p < 2; ++p) {
      int c = wv * 2 + p;
      async_load16(Ag + (size_t)(c * 16 + srow) * K + skc, &As[c * 512]);
      async_load16(Bg + (size_t)(c * 16 + srow) * K + skc, &Bs[c * 512]);
    }
    __syncthreads();
    bf16x8 af[4], bfr[4];
#pragma unroll
    for (int m = 0; m < 4; ++m) af[m] = *(const bf16x8*)&As[(wr + m * 16 + ar) * 32 + ak];
#pragma unroll
    for (int n = 0; n < 4; ++n) bfr[n] = *(const bf16x8*)&Bs[(wc + n * 16 + ar) * 32 + ak];
#pragma unroll
    for (int m = 0; m < 4; ++m)
#pragma unroll
      for (int n = 0; n < 4; ++n) acc[m][n] = MFMA16(af[m], bfr[n], acc[m][n]);
    __syncthreads();
  }
#pragma unroll
  for (int m = 0; m < 4; ++m) {
    int row = m0 + wr + m * 16 + (lane >> 4) * 4;
#pragma unroll
    for (int n = 0; n < 4; ++n) {
      int col = n0 + wc + n * 16 + ar;
      if (BF16OUT) {
        unsigned short* cp = (unsigned short*)Cv + (size_t)row * N + col;
#pragma unroll
        for (int j = 0; j < 4; ++j) cp[(size_t)j * N] = f2bf(acc[m][n][j]);
      } else {
        float* cp = (float*)Cv + (size_t)row * N + col;
#pragma unroll
        for (int j = 0; j < 4; ++j) cp[(size_t)j * N] = acc[m][n][j];
      }
    }
  }
}

// ---------------- RoPE apply + head split + V transpose (bf16 qkv in) -------
__global__ __launch_bounds__(256) void rope_kernel(const unsigned short* __restrict__ qkv,
                                                   const float* __restrict__ tc,
                                                   const float* __restrict__ ts,
                                                   unsigned short* __restrict__ qo,
                                                   unsigned short* __restrict__ ko,
                                                   unsigned short* __restrict__ vt) {
  const int S = 2048;
  const int bx = blockIdx.x;
  const int st = bx & 31, bh = bx >> 5;
  const int b = bh >> 4, h = bh & 15;
  const int t = threadIdx.x;
  const int sl = t >> 2, j0 = (t & 3) * 8;
  const int s = st * 64 + sl;
  const unsigned short* row = qkv + (size_t)(b * S + s) * 3072;
  float cv[8], sv[8];
#pragma unroll
  for (int i = 0; i < 8; ++i) {
    cv[i] = tc[s * 32 + j0 + i];
    sv[i] = ts[s * 32 + j0 + i];
  }
  __shared__ unsigned short vtile[64][66];
#pragma unroll
  for (int m = 0; m < 2; ++m) {
    const int col0 = m * 1024 + h * 64;
    const float qscale = (m == 0) ? 0.125f * 1.44269504088896340736f : 1.0f;
    bf16x8 lo8 = *(const bf16x8*)&row[col0 + j0];
    bf16x8 hi8 = *(const bf16x8*)&row[col0 + 32 + j0];
    bf16x8 outlo, outhi;
#pragma unroll
    for (int i = 0; i < 8; ++i) {
      float lo = b2f((unsigned short)lo8[i]), hi = b2f((unsigned short)hi8[i]);
      outlo[i] = (short)f2bf((lo * cv[i] - hi * sv[i]) * qscale);
      outhi[i] = (short)f2bf((hi * cv[i] + lo * sv[i]) * qscale);
    }
    unsigned short* dst = (m == 0 ? qo : ko) + (size_t)(bh * S + s) * 64;
    *(bf16x8*)&dst[j0] = outlo;
    *(bf16x8*)&dst[32 + j0] = outhi;
  }
  {
    const int col0 = 2048 + h * 64;
    bf16x8 v8a = *(const bf16x8*)&row[col0 + j0];
    bf16x8 v8b = *(const bf16x8*)&row[col0 + 32 + j0];
#pragma unroll
    for (int i = 0; i < 8; ++i) {
      vtile[j0 + i][sl] = (unsigned short)v8a[i];
      vtile[j0 + 32 + i][sl] = (unsigned short)v8b[i];
    }
  }
  __syncthreads();
  {
    const int hd = t >> 2, sc0 = (t & 3) * 16;
    unsigned short* dst = vt + ((size_t)bh * 64 + hd) * S + st * 64 + sc0;
    bf16x8 a, bv;
#pragma unroll
    for (int i = 0; i < 8; ++i) {
      a[i] = (short)vtile[hd][sc0 + i];
      bv[i] = (short)vtile[hd][sc0 + 8 + i];
    }
    *(bf16x8*)&dst[0] = a;
    *(bf16x8*)&dst[8] = bv;
  }
}

// ---------------- attention: block-cooperative LDS-staged K/V ----------------
// Block = 128 q-rows (4 waves x 32). 64-key tiles double-buffered in LDS via
// global_load_lds (async, zero VGPR - kills the serialized-register-load wall).
// XOR swizzle byte^((row&7)<<4) with pre-swizzled GLOBAL source (rule #21).
// stage(t+1) issued before compute(t); the __syncthreads after compute drains
// it -> a full tile of latency hiding the compiler cannot defeat.

__device__ __forceinline__ bf16x8 buildP(const unsigned* w, int tt, int hi) {
  const int base = (tt & 1) * 4 + (tt >> 1) * 8;
  unsigned wA = w[base], wB = w[base + 1], wC = w[base + 2], wD = w[base + 3];
  unsigned s1v = __shfl_xor(hi ? wA : wC, 32);
  unsigned s2v = __shfl_xor(hi ? wB : wD, 32);
  union { unsigned u[4]; bf16x8 v; } pw;
  pw.u[0] = hi ? s1v : wA;
  pw.u[1] = hi ? s2v : wB;
  pw.u[2] = hi ? wC : s1v;
  pw.u[3] = hi ? wD : s2v;
  return pw.v;
}

// stage one 64-key K tile (8KB, contiguous) + V tile (8KB, strided rows) into
// LDS, pre-swizzled source so that LDS[d] = tile[d ^ (((d>>7)&7)<<4)].
__device__ __forceinline__ void stage_tiles(const char* kg, const char* vg, int t,
                                            unsigned short* kb, unsigned short* vb,
                                            int wv, int lane) {
  const int lsw = ((lane >> 3) & 7) << 4;
#pragma unroll
  for (int p = 0; p < 2; ++p) {
    const int i = 2 * wv + p;
    const int d = i * 1024 + lane * 16;
    async_load16(kg + (size_t)t * 8192 + (d ^ lsw), (char*)kb + i * 1024);
    const int dim = i * 8 + (lane >> 3);
    const int key2 = (((lane & 7) ^ ((lane >> 3) & 7)) << 4);
    async_load16(vg + (size_t)dim * 4096 + (size_t)t * 128 + key2, (char*)vb + i * 1024);
  }
}

// 64-key tile from LDS; R13-proven dual-bank softmax body. off = qlow - 64t:
// off>=64 full; off in {0,32} -> mask key_local > off+ql.
__device__ __forceinline__ void super_lds(const unsigned short* kbuf, const unsigned short* vbuf,
                                          int ql, int hi, int off, const bf16x8 (&qf)[4],
                                          f32x16& a0, f32x16& a1, float& m_run, float& l_run) {
  const char* kb = (const char*)kbuf;
  const char* vb = (const char*)vbuf;
  const int rsw = (ql & 7) << 4;
  bf16x8 k0[4], k1[4];
#pragma unroll
  for (int s = 0; s < 4; ++s) {
    k0[s] = *(const bf16x8*)(kb + (((ql << 7) + (s << 5) + (hi << 4)) ^ rsw));
    k1[s] = *(const bf16x8*)(kb + ((((32 + ql) << 7) + (s << 5) + (hi << 4)) ^ rsw));
  }
  f32x16 s0 = zero16(), s1 = zero16();
  __builtin_amdgcn_s_setprio(1);
#pragma unroll
  for (int s = 0; s < 4; ++s) {
    s0 = MFMA32(k0[s], qf[s], s0);
    s1 = MFMA32(k1[s], qf[s], s1);
  }
  __builtin_amdgcn_s_setprio(0);

  bf16x8 v0[4], v1[4];
#pragma unroll
  for (int tt = 0; tt < 4; ++tt) {
    v0[tt] = *(const bf16x8*)(vb + (((ql << 7) + (tt << 5) + (hi << 4)) ^ rsw));
    v1[tt] = *(const bf16x8*)(vb + ((((32 + ql) << 7) + (tt << 5) + (hi << 4)) ^ rsw));
  }

  if (off < 64) {
#pragma unroll
    for (int r = 0; r < 16; ++r) {
      const int key = (r & 3) + 8 * (r >> 2) + 4 * hi;
      if (key > off + ql) s0[r] = -INFINITY;
      if (key + 32 > off + ql) s1[r] = -INFINITY;
    }
  }

  float p[8];
#pragma unroll
  for (int i = 0; i < 8; ++i)
    p[i] = fmaxf(fmaxf(s0[2 * i], s0[2 * i + 1]), fmaxf(s1[2 * i], s1[2 * i + 1]));
#pragma unroll
  for (int i = 0; i < 4; ++i) p[i] = fmaxf(p[i], p[i + 4]);
  float mx = fmaxf(fmaxf(p[0], p[1]), fmaxf(p[2], p[3]));
  mx = fmaxf(mx, __shfl_xor(mx, 32));
  const bool defer = __all(mx - m_run <= 8.0f) != 0;
  const float mn = defer ? m_run : fmaxf(m_run, mx);
  float r0 = 0.f, r1 = 0.f, r2 = 0.f, r3 = 0.f;
#pragma unroll
  for (int i = 0; i < 4; ++i) {
    float e0 = fexp2(s0[4 * i + 0] - mn); s0[4 * i + 0] = e0; r0 += e0;
    float e1 = fexp2(s0[4 * i + 1] - mn); s0[4 * i + 1] = e1; r1 += e1;
    float e2 = fexp2(s0[4 * i + 2] - mn); s0[4 * i + 2] = e2; r2 += e2;
    float e3 = fexp2(s0[4 * i + 3] - mn); s0[4 * i + 3] = e3; r3 += e3;
  }
#pragma unroll
  for (int i = 0; i < 4; ++i) {
    float e0 = fexp2(s1[4 * i + 0] - mn); s1[4 * i + 0] = e0; r0 += e0;
    float e1 = fexp2(s1[4 * i + 1] - mn); s1[4 * i + 1] = e1; r1 += e1;
    float e2 = fexp2(s1[4 * i + 2] - mn); s1[4 * i + 2] = e2; r2 += e2;
    float e3 = fexp2(s1[4 * i + 3] - mn); s1[4 * i + 3] = e3; r3 += e3;
  }
  const float rs = (r0 + r1) + (r2 + r3);
  if (defer) {
    l_run += rs;
  } else {
    const float scl = fexp2(m_run - mn);
    m_run = mn;
    l_run = l_run * scl + rs;
#pragma unroll
    for (int r = 0; r < 16; ++r) { a0[r] *= scl; a1[r] *= scl; }
  }
  unsigned w[16];
#pragma unroll
  for (int i = 0; i < 8; ++i) {
    w[i] = cvt_pk(s0[2 * i], s0[2 * i + 1]);
    w[8 + i] = cvt_pk(s1[2 * i], s1[2 * i + 1]);
  }
  __builtin_amdgcn_s_setprio(1);
#pragma unroll
  for (int tt = 0; tt < 4; ++tt) {
    bf16x8 pp = buildP(w, tt, hi);
    a0 = MFMA32(v0[tt], pp, a0);
    a1 = MFMA32(v1[tt], pp, a1);
  }
  __builtin_amdgcn_s_setprio(0);
}

// grid: 1024 blocks = 64 bh x 16 qb (descending qb), XCD-swizzled.
__global__ __launch_bounds__(256, 3) void attn_kernel(const unsigned short* __restrict__ Q,
                                                      const unsigned short* __restrict__ Kk,
                                                      const unsigned short* __restrict__ Vt,
                                                      unsigned short* __restrict__ O) {
  const int S = 2048;
  const int tid = threadIdx.x, lane = tid & 63, wv = tid >> 6;
  const int swz = (blockIdx.x & 7) * 128 + (blockIdx.x >> 3);
  const int bh = swz >> 4;
  const int qb = 15 - (swz & 15);   // heavy blocks dispatched first
  const int b = bh >> 4, h = bh & 15;
  const int ql = lane & 31, hi = lane >> 5;
  const int qlow = qb * 128 + wv * 32;

  __shared__ unsigned short kbuf[2][4096];
  __shared__ unsigned short vbuf[2][4096];

  const unsigned short* qh = Q + (size_t)bh * S * 64;
  const char* kg = (const char*)(Kk + (size_t)bh * S * 64);
  const char* vg = (const char*)(Vt + (size_t)bh * 64 * S);

  bf16x8 qf[4];
#pragma unroll
  for (int s = 0; s < 4; ++s)
    qf[s] = *(const bf16x8*)&qh[(size_t)(qlow + ql) * 64 + s * 16 + hi * 8];

  f32x16 a0 = zero16(), a1 = zero16();
  float m_run = -INFINITY, l_run = 0.f;

  const int nt = 2 * qb + 2;
  stage_tiles(kg, vg, 0, &kbuf[0][0], &vbuf[0][0], wv, lane);
  __syncthreads();
  int buf = 0;
  for (int t = 0; t < nt; ++t) {
    if (t + 1 < nt)
      stage_tiles(kg, vg, t + 1, &kbuf[buf ^ 1][0], &vbuf[buf ^ 1][0], wv, lane);
    if (t * 64 <= qlow + 31) {
      const int off = qlow - t * 64;
      super_lds(&kbuf[buf][0], &vbuf[buf][0], ql, hi, off, qf, a0, a1, m_run, l_run);
    }
    __syncthreads();
    buf ^= 1;
  }

  l_run += __shfl_xor(l_run, 32);
  const float inv = 1.f / l_run;
  unsigned short* orow = O + (size_t)(b * S + qlow + ql) * 1024 + h * 64;
#pragma unroll
  for (int r = 0; r < 16; ++r) {
    int d = (r & 3) + 8 * (r >> 2) + 4 * hi;
    orow[d] = f2bf(a0[r] * inv);
    orow[32 + d] = f2bf(a1[r] * inv);
  }
}

extern "C" void kernel_launch(void* const* d_in, const int* in_sizes, int n_in,
                              void* d_out, int out_size, void* d_ws, size_t ws_size,
                              hipStream_t stream) {
  const float* x = (const float*)d_in[0];
  const float* Wqkv = (const float*)d_in[1];
  const float* Wout = (const float*)d_in[2];
  float* out = (float*)d_out;

  char* ws = (char*)d_ws;
  size_t off = 0;
  auto take = [&](size_t bytes) {
    void* p = ws + off;
    off += (bytes + 255) & ~(size_t)255;
    return p;
  };
  float* tc = (float*)take(2048 * 32 * 4);
  float* tsn = (float*)take(2048 * 32 * 4);
  unsigned short* xbf = (unsigned short*)take((size_t)8192 * 1024 * 2);
  unsigned short* wqkvT = (unsigned short*)take((size_t)3072 * 1024 * 2);
  unsigned short* woutT = (unsigned short*)take((size_t)1024 * 1024 * 2);
  unsigned short* qkvb = (unsigned short*)take((size_t)8192 * 3072 * 2);
  unsigned short* qb_ = (unsigned short*)take((size_t)64 * 2048 * 64 * 2);
  unsigned short* kb_ = (unsigned short*)take((size_t)64 * 2048 * 64 * 2);
  unsigned short* vt = (unsigned short*)take((size_t)64 * 64 * 2048 * 2);
  unsigned short* attn = (unsigned short*)take((size_t)8192 * 1024 * 2);

  rope_table_kernel<<<256, 256, 0, stream>>>(tc, tsn);
  cvt_kernel<<<(2097152 + 255) / 256, 256, 0, stream>>>(x, xbf, 2097152);
  {
    dim3 g(96, 32);
    transpose_cvt<<<g, 256, 0, stream>>>(Wqkv, wqkvT, 1024, 3072);
  }
  {
    dim3 g(32, 32);
    transpose_cvt<<<g, 256, 0, stream>>>(Wout, woutT, 1024, 1024);
  }
  {
    dim3 g(24, 64);
    gemm_bt<true><<<g, 256, 0, stream>>>(xbf, wqkvT, qkvb, 8192, 3072, 1024);
  }
  rope_kernel<<<2048, 256, 0, stream>>>(qkvb, tc, tsn, qb_, kb_, vt);
  attn_kernel<<<1024, 256, 0, stream>>>(qb_, kb_, vt, attn);
  {
    dim3 g(8, 64);
    gemm_bt<false><<<g, 256, 0, stream>>>(attn, woutT, out, 8192, 1024, 1024);
  }
}

// Round 17
// 218.944 us; speedup vs baseline: 4.3168x; 1.0164x over previous
//
#include <hip/hip_runtime.h>
#include <hip/hip_bf16.h>
#include <math.h>

typedef __attribute__((ext_vector_type(8))) short bf16x8;
typedef __attribute__((ext_vector_type(4))) short short4v;
typedef __attribute__((ext_vector_type(4))) float f32x4;
typedef __attribute__((ext_vector_type(16))) float f32x16;

#define MFMA16(a,b,c) __builtin_amdgcn_mfma_f32_16x16x32_bf16(a,b,c,0,0,0)
#define MFMA32(a,b,c) __builtin_amdgcn_mfma_f32_32x32x16_bf16(a,b,c,0,0,0)

__device__ __forceinline__ unsigned short f2bf(float f) {
  union { float f; unsigned u; } v; v.f = f;
  unsigned r = v.u + 0x7FFFu + ((v.u >> 16) & 1u);
  return (unsigned short)(r >> 16);
}
__device__ __forceinline__ float b2f(unsigned short u) {
  union { unsigned u; float f; } v; v.u = (unsigned)u << 16; return v.f;
}

__device__ __forceinline__ unsigned cvt_pk(float lo, float hi) {
  unsigned r;
  asm("v_cvt_pk_bf16_f32 %0, %1, %2" : "=v"(r) : "v"(lo), "v"(hi));
  return r;
}
__device__ __forceinline__ float fexp2(float x) {
  float r;
  asm("v_exp_f32 %0, %1" : "=v"(r) : "v"(x));
  return r;
}

__device__ __forceinline__ void async_load16(const void* g, void* lds) {
  __builtin_amdgcn_global_load_lds(
      (const __attribute__((address_space(1))) unsigned int*)g,
      (__attribute__((address_space(3))) unsigned int*)lds, 16, 0, 0);
}

__device__ __forceinline__ f32x16 zero16() {
  f32x16 z;
#pragma unroll
  for (int i = 0; i < 16; ++i) z[i] = 0.f;
  return z;
}

// ---------------- RoPE table ----------------
__global__ void rope_table_kernel(float* __restrict__ tc, float* __restrict__ ts) {
  int i = blockIdx.x * 256 + threadIdx.x;
  if (i >= 2048 * 32) return;
  int s = i >> 5, j = i & 31;
  double invf = pow(10000.0, -(double)(2 * j) / 64.0);
  double ang = (double)s * invf;
  tc[i] = (float)cos(ang);
  ts[i] = (float)sin(ang);
}

// ---------------- fp32 -> bf16 elementwise ----------------
__global__ __launch_bounds__(256) void cvt_kernel(const float* __restrict__ in,
                                                  unsigned short* __restrict__ out, int n4) {
  int i = blockIdx.x * 256 + threadIdx.x;
  if (i >= n4) return;
  float4 v = ((const float4*)in)[i];
  short4v o;
  o[0] = (short)f2bf(v.x); o[1] = (short)f2bf(v.y);
  o[2] = (short)f2bf(v.z); o[3] = (short)f2bf(v.w);
  *(short4v*)&out[(size_t)i * 4] = o;
}

// ---------------- fp32 [R][C] -> bf16 [C][R] transpose ----------------
__global__ __launch_bounds__(256) void transpose_cvt(const float* __restrict__ in,
                                                     unsigned short* __restrict__ out,
                                                     int R, int C) {
  __shared__ float tile[32][33];
  const int bx = blockIdx.x * 32, by = blockIdx.y * 32;
  const int tx = threadIdx.x & 31, ty0 = threadIdx.x >> 5;
#pragma unroll
  for (int p = 0; p < 4; ++p) {
    int r = ty0 + p * 8;
    tile[r][tx] = in[(size_t)(by + r) * C + bx + tx];
  }
  __syncthreads();
#pragma unroll
  for (int p = 0; p < 4; ++p) {
    int r = ty0 + p * 8;
    out[(size_t)(bx + r) * R + by + tx] = f2bf(tile[tx][r]);
  }
}

// ---------------- GEMM (m97 structure); BF16OUT selects output dtype ----------
template<bool BF16OUT>
__global__ __launch_bounds__(256) void gemm_bt(const unsigned short* __restrict__ A,
                                               const unsigned short* __restrict__ Bt,
                                               void* __restrict__ Cv,
                                               int M, int N, int K) {
  __shared__ unsigned short As[128 * 32];
  __shared__ unsigned short Bs[128 * 32];
  const int t = threadIdx.x, lane = t & 63, wv = t >> 6;
  const int bn = blockIdx.x, bm = blockIdx.y;
  const int m0 = bm * 128, n0 = bn * 128;
  f32x4 acc[4][4];
#pragma unroll
  for (int m = 0; m < 4; ++m)
#pragma unroll
    for (int n = 0; n < 4; ++n) acc[m][n] = (f32x4){0.f, 0.f, 0.f, 0.f};
  const int wr = (wv >> 1) * 64, wc = (wv & 1) * 64;
  const int ar = lane & 15, ak = (lane >> 4) * 8;
  const int srow = lane >> 2, skc = (lane & 3) * 8;
  const int nkt = K >> 5;
  for (int kt = 0; kt < nkt; ++kt) {
    const unsigned short* Ag = A + (size_t)m0 * K + kt * 32;
    const unsigned short* Bg = Bt + (size_t)n0 * K + kt * 32;
#pragma unroll
    for (int p = 0; p < 2; ++p) {
      int c = wv * 2 + p;
      async_load16(Ag + (size_t)(c * 16 + srow) * K + skc, &As[c * 512]);
      async_load16(Bg + (size_t)(c * 16 + srow) * K + skc, &Bs[c * 512]);
    }
    __syncthreads();
    bf16x8 af[4], bfr[4];
#pragma unroll
    for (int m = 0; m < 4; ++m) af[m] = *(const bf16x8*)&As[(wr + m * 16 + ar) * 32 + ak];
#pragma unroll
    for (int n = 0; n < 4; ++n) bfr[n] = *(const bf16x8*)&Bs[(wc + n * 16 + ar) * 32 + ak];
#pragma unroll
    for (int m = 0; m < 4; ++m)
#pragma unroll
      for (int n = 0; n < 4; ++n) acc[m][n] = MFMA16(af[m], bfr[n], acc[m][n]);
    __syncthreads();
  }
#pragma unroll
  for (int m = 0; m < 4; ++m) {
    int row = m0 + wr + m * 16 + (lane >> 4) * 4;
#pragma unroll
    for (int n = 0; n < 4; ++n) {
      int col = n0 + wc + n * 16 + ar;
      if (BF16OUT) {
        unsigned short* cp = (unsigned short*)Cv + (size_t)row * N + col;
#pragma unroll
        for (int j = 0; j < 4; ++j) cp[(size_t)j * N] = f2bf(acc[m][n][j]);
      } else {
        float* cp = (float*)Cv + (size_t)row * N + col;
#pragma unroll
        for (int j = 0; j < 4; ++j) cp[(size_t)j * N] = acc[m][n][j];
      }
    }
  }
}

// ---------------- RoPE apply + head split + V transpose (bf16 qkv in) -------
__global__ __launch_bounds__(256) void rope_kernel(const unsigned short* __restrict__ qkv,
                                                   const float* __restrict__ tc,
                                                   const float* __restrict__ ts,
                                                   unsigned short* __restrict__ qo,
                                                   unsigned short* __restrict__ ko,
                                                   unsigned short* __restrict__ vt) {
  const int S = 2048;
  const int bx = blockIdx.x;
  const int st = bx & 31, bh = bx >> 5;
  const int b = bh >> 4, h = bh & 15;
  const int t = threadIdx.x;
  const int sl = t >> 2, j0 = (t & 3) * 8;
  const int s = st * 64 + sl;
  const unsigned short* row = qkv + (size_t)(b * S + s) * 3072;
  float cv[8], sv[8];
#pragma unroll
  for (int i = 0; i < 8; ++i) {
    cv[i] = tc[s * 32 + j0 + i];
    sv[i] = ts[s * 32 + j0 + i];
  }
  __shared__ unsigned short vtile[64][66];
#pragma unroll
  for (int m = 0; m < 2; ++m) {
    const int col0 = m * 1024 + h * 64;
    const float qscale = (m == 0) ? 0.125f * 1.44269504088896340736f : 1.0f;
    bf16x8 lo8 = *(const bf16x8*)&row[col0 + j0];
    bf16x8 hi8 = *(const bf16x8*)&row[col0 + 32 + j0];
    bf16x8 outlo, outhi;
#pragma unroll
    for (int i = 0; i < 8; ++i) {
      float lo = b2f((unsigned short)lo8[i]), hi = b2f((unsigned short)hi8[i]);
      outlo[i] = (short)f2bf((lo * cv[i] - hi * sv[i]) * qscale);
      outhi[i] = (short)f2bf((hi * cv[i] + lo * sv[i]) * qscale);
    }
    unsigned short* dst = (m == 0 ? qo : ko) + (size_t)(bh * S + s) * 64;
    *(bf16x8*)&dst[j0] = outlo;
    *(bf16x8*)&dst[32 + j0] = outhi;
  }
  {
    const int col0 = 2048 + h * 64;
    bf16x8 v8a = *(const bf16x8*)&row[col0 + j0];
    bf16x8 v8b = *(const bf16x8*)&row[col0 + 32 + j0];
#pragma unroll
    for (int i = 0; i < 8; ++i) {
      vtile[j0 + i][sl] = (unsigned short)v8a[i];
      vtile[j0 + 32 + i][sl] = (unsigned short)v8b[i];
    }
  }
  __syncthreads();
  {
    const int hd = t >> 2, sc0 = (t & 3) * 16;
    unsigned short* dst = vt + ((size_t)bh * 64 + hd) * S + st * 64 + sc0;
    bf16x8 a, bv;
#pragma unroll
    for (int i = 0; i < 8; ++i) {
      a[i] = (short)vtile[hd][sc0 + i];
      bv[i] = (short)vtile[hd][sc0 + 8 + i];
    }
    *(bf16x8*)&dst[0] = a;
    *(bf16x8*)&dst[8] = bv;
  }
}

// ---------------- attention: block-cooperative LDS-staged K/V ----------------
// R16 structure (LDS double-buffered async staging, XOR swizzle, dual-bank
// softmax). One change: balanced block->CU mapping so each CU's 4 resident
// blocks sum to a constant 68 tile-units (was 8..128 -> tail-bound).

__device__ __forceinline__ bf16x8 buildP(const unsigned* w, int tt, int hi) {
  const int base = (tt & 1) * 4 + (tt >> 1) * 8;
  unsigned wA = w[base], wB = w[base + 1], wC = w[base + 2], wD = w[base + 3];
  unsigned s1v = __shfl_xor(hi ? wA : wC, 32);
  unsigned s2v = __shfl_xor(hi ? wB : wD, 32);
  union { unsigned u[4]; bf16x8 v; } pw;
  pw.u[0] = hi ? s1v : wA;
  pw.u[1] = hi ? s2v : wB;
  pw.u[2] = hi ? wC : s1v;
  pw.u[3] = hi ? wD : s2v;
  return pw.v;
}

// stage one 64-key K tile (8KB) + V tile (8KB) into LDS, pre-swizzled source
// so that LDS[d] = tile[d ^ (((d>>7)&7)<<4)].
__device__ __forceinline__ void stage_tiles(const char* kg, const char* vg, int t,
                                            unsigned short* kb, unsigned short* vb,
                                            int wv, int lane) {
  const int lsw = ((lane >> 3) & 7) << 4;
#pragma unroll
  for (int p = 0; p < 2; ++p) {
    const int i = 2 * wv + p;
    const int d = i * 1024 + lane * 16;
    async_load16(kg + (size_t)t * 8192 + (d ^ lsw), (char*)kb + i * 1024);
    const int dim = i * 8 + (lane >> 3);
    const int key2 = (((lane & 7) ^ ((lane >> 3) & 7)) << 4);
    async_load16(vg + (size_t)dim * 4096 + (size_t)t * 128 + key2, (char*)vb + i * 1024);
  }
}

// 64-key tile from LDS; dual-bank softmax body. off = qlow - 64t:
// off>=64 full; off in {0,32} -> mask key_local > off+ql.
__device__ __forceinline__ void super_lds(const unsigned short* kbuf, const unsigned short* vbuf,
                                          int ql, int hi, int off, const bf16x8 (&qf)[4],
                                          f32x16& a0, f32x16& a1, float& m_run, float& l_run) {
  const char* kb = (const char*)kbuf;
  const char* vb = (const char*)vbuf;
  const int rsw = (ql & 7) << 4;
  bf16x8 k0[4], k1[4];
#pragma unroll
  for (int s = 0; s < 4; ++s) {
    k0[s] = *(const bf16x8*)(kb + (((ql << 7) + (s << 5) + (hi << 4)) ^ rsw));
    k1[s] = *(const bf16x8*)(kb + ((((32 + ql) << 7) + (s << 5) + (hi << 4)) ^ rsw));
  }
  f32x16 s0 = zero16(), s1 = zero16();
  __builtin_amdgcn_s_setprio(1);
#pragma unroll
  for (int s = 0; s < 4; ++s) {
    s0 = MFMA32(k0[s], qf[s], s0);
    s1 = MFMA32(k1[s], qf[s], s1);
  }
  __builtin_amdgcn_s_setprio(0);

  bf16x8 v0[4], v1[4];
#pragma unroll
  for (int tt = 0; tt < 4; ++tt) {
    v0[tt] = *(const bf16x8*)(vb + (((ql << 7) + (tt << 5) + (hi << 4)) ^ rsw));
    v1[tt] = *(const bf16x8*)(vb + ((((32 + ql) << 7) + (tt << 5) + (hi << 4)) ^ rsw));
  }

  if (off < 64) {
#pragma unroll
    for (int r = 0; r < 16; ++r) {
      const int key = (r & 3) + 8 * (r >> 2) + 4 * hi;
      if (key > off + ql) s0[r] = -INFINITY;
      if (key + 32 > off + ql) s1[r] = -INFINITY;
    }
  }

  float p[8];
#pragma unroll
  for (int i = 0; i < 8; ++i)
    p[i] = fmaxf(fmaxf(s0[2 * i], s0[2 * i + 1]), fmaxf(s1[2 * i], s1[2 * i + 1]));
#pragma unroll
  for (int i = 0; i < 4; ++i) p[i] = fmaxf(p[i], p[i + 4]);
  float mx = fmaxf(fmaxf(p[0], p[1]), fmaxf(p[2], p[3]));
  mx = fmaxf(mx, __shfl_xor(mx, 32));
  const bool defer = __all(mx - m_run <= 8.0f) != 0;
  const float mn = defer ? m_run : fmaxf(m_run, mx);
  float r0 = 0.f, r1 = 0.f, r2 = 0.f, r3 = 0.f;
#pragma unroll
  for (int i = 0; i < 4; ++i) {
    float e0 = fexp2(s0[4 * i + 0] - mn); s0[4 * i + 0] = e0; r0 += e0;
    float e1 = fexp2(s0[4 * i + 1] - mn); s0[4 * i + 1] = e1; r1 += e1;
    float e2 = fexp2(s0[4 * i + 2] - mn); s0[4 * i + 2] = e2; r2 += e2;
    float e3 = fexp2(s0[4 * i + 3] - mn); s0[4 * i + 3] = e3; r3 += e3;
  }
#pragma unroll
  for (int i = 0; i < 4; ++i) {
    float e0 = fexp2(s1[4 * i + 0] - mn); s1[4 * i + 0] = e0; r0 += e0;
    float e1 = fexp2(s1[4 * i + 1] - mn); s1[4 * i + 1] = e1; r1 += e1;
    float e2 = fexp2(s1[4 * i + 2] - mn); s1[4 * i + 2] = e2; r2 += e2;
    float e3 = fexp2(s1[4 * i + 3] - mn); s1[4 * i + 3] = e3; r3 += e3;
  }
  const float rs = (r0 + r1) + (r2 + r3);
  if (defer) {
    l_run += rs;
  } else {
    const float scl = fexp2(m_run - mn);
    m_run = mn;
    l_run = l_run * scl + rs;
#pragma unroll
    for (int r = 0; r < 16; ++r) { a0[r] *= scl; a1[r] *= scl; }
  }
  unsigned w[16];
#pragma unroll
  for (int i = 0; i < 8; ++i) {
    w[i] = cvt_pk(s0[2 * i], s0[2 * i + 1]);
    w[8 + i] = cvt_pk(s1[2 * i], s1[2 * i + 1]);
  }
  __builtin_amdgcn_s_setprio(1);
#pragma unroll
  for (int tt = 0; tt < 4; ++tt) {
    bf16x8 pp = buildP(w, tt, hi);
    a0 = MFMA32(v0[tt], pp, a0);
    a1 = MFMA32(v1[tt], pp, a1);
  }
  __builtin_amdgcn_s_setprio(0);
}

// grid: 1024 blocks. Balanced mapping: within each XCD chunk of 128 blocks,
// i = (r,jb,jq); bh_local = 2r+jb, qb = (r&1)?15-jq:jq. Under round-robin
// dispatch each CU's 4 blocks pair qb {x,15-x,x,15-x} -> constant 68 units.
__global__ __launch_bounds__(256, 3) void attn_kernel(const unsigned short* __restrict__ Q,
                                                      const unsigned short* __restrict__ Kk,
                                                      const unsigned short* __restrict__ Vt,
                                                      unsigned short* __restrict__ O) {
  const int S = 2048;
  const int tid = threadIdx.x, lane = tid & 63, wv = tid >> 6;
  const int xcd = blockIdx.x & 7;
  const int i = blockIdx.x >> 3;          // 0..127 within XCD chunk
  const int r = i >> 5, j = i & 31;
  const int jb = j >> 4, jq = j & 15;
  const int bh = xcd * 8 + 2 * r + jb;
  const int qb = (r & 1) ? 15 - jq : jq;
  const int b = bh >> 4, h = bh & 15;
  const int ql = lane & 31, hi = lane >> 5;
  const int qlow = qb * 128 + wv * 32;

  __shared__ unsigned short kbuf[2][4096];
  __shared__ unsigned short vbuf[2][4096];

  const unsigned short* qh = Q + (size_t)bh * S * 64;
  const char* kg = (const char*)(Kk + (size_t)bh * S * 64);
  const char* vg = (const char*)(Vt + (size_t)bh * 64 * S);

  bf16x8 qf[4];
#pragma unroll
  for (int s = 0; s < 4; ++s)
    qf[s] = *(const bf16x8*)&qh[(size_t)(qlow + ql) * 64 + s * 16 + hi * 8];

  f32x16 a0 = zero16(), a1 = zero16();
  float m_run = -INFINITY, l_run = 0.f;

  const int nt = 2 * qb + 2;
  stage_tiles(kg, vg, 0, &kbuf[0][0], &vbuf[0][0], wv, lane);
  __syncthreads();
  int buf = 0;
  for (int t = 0; t < nt; ++t) {
    if (t + 1 < nt)
      stage_tiles(kg, vg, t + 1, &kbuf[buf ^ 1][0], &vbuf[buf ^ 1][0], wv, lane);
    if (t * 64 <= qlow + 31) {
      const int off = qlow - t * 64;
      super_lds(&kbuf[buf][0], &vbuf[buf][0], ql, hi, off, qf, a0, a1, m_run, l_run);
    }
    __syncthreads();
    buf ^= 1;
  }

  l_run += __shfl_xor(l_run, 32);
  const float inv = 1.f / l_run;
  unsigned short* orow = O + (size_t)(b * S + qlow + ql) * 1024 + h * 64;
#pragma unroll
  for (int r2 = 0; r2 < 16; ++r2) {
    int d = (r2 & 3) + 8 * (r2 >> 2) + 4 * hi;
    orow[d] = f2bf(a0[r2] * inv);
    orow[32 + d] = f2bf(a1[r2] * inv);
  }
}

extern "C" void kernel_launch(void* const* d_in, const int* in_sizes, int n_in,
                              void* d_out, int out_size, void* d_ws, size_t ws_size,
                              hipStream_t stream) {
  const float* x = (const float*)d_in[0];
  const float* Wqkv = (const float*)d_in[1];
  const float* Wout = (const float*)d_in[2];
  float* out = (float*)d_out;

  char* ws = (char*)d_ws;
  size_t off = 0;
  auto take = [&](size_t bytes) {
    void* p = ws + off;
    off += (bytes + 255) & ~(size_t)255;
    return p;
  };
  float* tc = (float*)take(2048 * 32 * 4);
  float* tsn = (float*)take(2048 * 32 * 4);
  unsigned short* xbf = (unsigned short*)take((size_t)8192 * 1024 * 2);
  unsigned short* wqkvT = (unsigned short*)take((size_t)3072 * 1024 * 2);
  unsigned short* woutT = (unsigned short*)take((size_t)1024 * 1024 * 2);
  unsigned short* qkvb = (unsigned short*)take((size_t)8192 * 3072 * 2);
  unsigned short* qb_ = (unsigned short*)take((size_t)64 * 2048 * 64 * 2);
  unsigned short* kb_ = (unsigned short*)take((size_t)64 * 2048 * 64 * 2);
  unsigned short* vt = (unsigned short*)take((size_t)64 * 64 * 2048 * 2);
  unsigned short* attn = (unsigned short*)take((size_t)8192 * 1024 * 2);

  rope_table_kernel<<<256, 256, 0, stream>>>(tc, tsn);
  cvt_kernel<<<(2097152 + 255) / 256, 256, 0, stream>>>(x, xbf, 2097152);
  {
    dim3 g(96, 32);
    transpose_cvt<<<g, 256, 0, stream>>>(Wqkv, wqkvT, 1024, 3072);
  }
  {
    dim3 g(32, 32);
    transpose_cvt<<<g, 256, 0, stream>>>(Wout, woutT, 1024, 1024);
  }
  {
    dim3 g(24, 64);
    gemm_bt<true><<<g, 256, 0, stream>>>(xbf, wqkvT, qkvb, 8192, 3072, 1024);
  }
  rope_kernel<<<2048, 256, 0, stream>>>(qkvb, tc, tsn, qb_, kb_, vt);
  attn_kernel<<<1024, 256, 0, stream>>>(qb_, kb_, vt, attn);
  {
    dim3 g(8, 64);
    gemm_bt<false><<<g, 256, 0, stream>>>(attn, woutT, out, 8192, 1024, 1024);
  }
}

// Round 18
// 210.970 us; speedup vs baseline: 4.4800x; 1.0378x over previous
//
#include <hip/hip_runtime.h>
#include <hip/hip_bf16.h>
#include <math.h>

typedef __attribute__((ext_vector_type(8))) short bf16x8;
typedef __attribute__((ext_vector_type(4))) short short4v;
typedef __attribute__((ext_vector_type(4))) float f32x4;
typedef __attribute__((ext_vector_type(16))) float f32x16;

#define MFMA16(a,b,c) __builtin_amdgcn_mfma_f32_16x16x32_bf16(a,b,c,0,0,0)
#define MFMA32(a,b,c) __builtin_amdgcn_mfma_f32_32x32x16_bf16(a,b,c,0,0,0)

__device__ __forceinline__ unsigned short f2bf(float f) {
  union { float f; unsigned u; } v; v.f = f;
  unsigned r = v.u + 0x7FFFu + ((v.u >> 16) & 1u);
  return (unsigned short)(r >> 16);
}
__device__ __forceinline__ float b2f(unsigned short u) {
  union { unsigned u; float f; } v; v.u = (unsigned)u << 16; return v.f;
}

__device__ __forceinline__ unsigned cvt_pk(float lo, float hi) {
  unsigned r;
  asm("v_cvt_pk_bf16_f32 %0, %1, %2" : "=v"(r) : "v"(lo), "v"(hi));
  return r;
}
__device__ __forceinline__ float fexp2(float x) {
  float r;
  asm("v_exp_f32 %0, %1" : "=v"(r) : "v"(x));
  return r;
}

__device__ __forceinline__ void async_load16(const void* g, void* lds) {
  __builtin_amdgcn_global_load_lds(
      (const __attribute__((address_space(1))) unsigned int*)g,
      (__attribute__((address_space(3))) unsigned int*)lds, 16, 0, 0);
}

__device__ __forceinline__ f32x16 zero16() {
  f32x16 z;
#pragma unroll
  for (int i = 0; i < 16; ++i) z[i] = 0.f;
  return z;
}

// ---------------- RoPE table ----------------
__global__ void rope_table_kernel(float* __restrict__ tc, float* __restrict__ ts) {
  int i = blockIdx.x * 256 + threadIdx.x;
  if (i >= 2048 * 32) return;
  int s = i >> 5, j = i & 31;
  double invf = pow(10000.0, -(double)(2 * j) / 64.0);
  double ang = (double)s * invf;
  tc[i] = (float)cos(ang);
  ts[i] = (float)sin(ang);
}

// ---------------- fp32 -> bf16 elementwise ----------------
__global__ __launch_bounds__(256) void cvt_kernel(const float* __restrict__ in,
                                                  unsigned short* __restrict__ out, int n4) {
  int i = blockIdx.x * 256 + threadIdx.x;
  if (i >= n4) return;
  float4 v = ((const float4*)in)[i];
  short4v o;
  o[0] = (short)f2bf(v.x); o[1] = (short)f2bf(v.y);
  o[2] = (short)f2bf(v.z); o[3] = (short)f2bf(v.w);
  *(short4v*)&out[(size_t)i * 4] = o;
}

// ---------------- fp32 [R][C] -> bf16 [C][R] transpose ----------------
__global__ __launch_bounds__(256) void transpose_cvt(const float* __restrict__ in,
                                                     unsigned short* __restrict__ out,
                                                     int R, int C) {
  __shared__ float tile[32][33];
  const int bx = blockIdx.x * 32, by = blockIdx.y * 32;
  const int tx = threadIdx.x & 31, ty0 = threadIdx.x >> 5;
#pragma unroll
  for (int p = 0; p < 4; ++p) {
    int r = ty0 + p * 8;
    tile[r][tx] = in[(size_t)(by + r) * C + bx + tx];
  }
  __syncthreads();
#pragma unroll
  for (int p = 0; p < 4; ++p) {
    int r = ty0 + p * 8;
    out[(size_t)(bx + r) * R + by + tx] = f2bf(tile[tx][r]);
  }
}

// ---------------- GEMM m97 (for GEMM2); BF16OUT selects output dtype ----------
template<bool BF16OUT>
__global__ __launch_bounds__(256) void gemm_bt(const unsigned short* __restrict__ A,
                                               const unsigned short* __restrict__ Bt,
                                               void* __restrict__ Cv,
                                               int M, int N, int K) {
  __shared__ unsigned short As[128 * 32];
  __shared__ unsigned short Bs[128 * 32];
  const int t = threadIdx.x, lane = t & 63, wv = t >> 6;
  const int bn = blockIdx.x, bm = blockIdx.y;
  const int m0 = bm * 128, n0 = bn * 128;
  f32x4 acc[4][4];
#pragma unroll
  for (int m = 0; m < 4; ++m)
#pragma unroll
    for (int n = 0; n < 4; ++n) acc[m][n] = (f32x4){0.f, 0.f, 0.f, 0.f};
  const int wr = (wv >> 1) * 64, wc = (wv & 1) * 64;
  const int ar = lane & 15, ak = (lane >> 4) * 8;
  const int srow = lane >> 2, skc = (lane & 3) * 8;
  const int nkt = K >> 5;
  for (int kt = 0; kt < nkt; ++kt) {
    const unsigned short* Ag = A + (size_t)m0 * K + kt * 32;
    const unsigned short* Bg = Bt + (size_t)n0 * K + kt * 32;
#pragma unroll
    for (int p = 0; p < 2; ++p) {
      int c = wv * 2 + p;
      async_load16(Ag + (size_t)(c * 16 + srow) * K + skc, &As[c * 512]);
      async_load16(Bg + (size_t)(c * 16 + srow) * K + skc, &Bs[c * 512]);
    }
    __syncthreads();
    bf16x8 af[4], bfr[4];
#pragma unroll
    for (int m = 0; m < 4; ++m) af[m] = *(const bf16x8*)&As[(wr + m * 16 + ar) * 32 + ak];
#pragma unroll
    for (int n = 0; n < 4; ++n) bfr[n] = *(const bf16x8*)&Bs[(wc + n * 16 + ar) * 32 + ak];
#pragma unroll
    for (int m = 0; m < 4; ++m)
#pragma unroll
      for (int n = 0; n < 4; ++n) acc[m][n] = MFMA16(af[m], bfr[n], acc[m][n]);
    __syncthreads();
  }
#pragma unroll
  for (int m = 0; m < 4; ++m) {
    int row = m0 + wr + m * 16 + (lane >> 4) * 4;
#pragma unroll
    for (int n = 0; n < 4; ++n) {
      int col = n0 + wc + n * 16 + ar;
      if (BF16OUT) {
        unsigned short* cp = (unsigned short*)Cv + (size_t)row * N + col;
#pragma unroll
        for (int j = 0; j < 4; ++j) cp[(size_t)j * N] = f2bf(acc[m][n][j]);
      } else {
        float* cp = (float*)Cv + (size_t)row * N + col;
#pragma unroll
        for (int j = 0; j < 4; ++j) cp[(size_t)j * N] = acc[m][n][j];
      }
    }
  }
}

// ---------------- GEMM 256x256 8-phase (T2+T3+T4+T5), bf16 out ----------------
// 512 threads = 8 waves (2M x 4N), per-wave C = 128x64 = acc[8][4].
// LDS 128KB: 2 bufs x {B.k0, A.k0, B.k1, A.k1} 16KB chunks ([256 rows][32 k]).
// Swizzle: w ^= ((row>>1)&3)<<4 (both sides: pre-swizzled global source).
// Per phase: ds_reads + 1 half-tile stage + raw barrier + 16 MFMA + barrier.
// vmcnt(6) only at phases 4/8: 3 chunks stay in flight across barriers.
__global__ __launch_bounds__(512, 2) void gemm8p(const unsigned short* __restrict__ A,
                                                 const unsigned short* __restrict__ Bt,
                                                 unsigned short* __restrict__ C,
                                                 int M, int N, int K) {
  __shared__ char lds[131072];
  const int tid = threadIdx.x, lane = tid & 63, wv = tid >> 6;
  const int wr = wv >> 2, wc = wv & 3;
  const int m0 = blockIdx.y * 256, n0 = blockIdx.x * 256;
  const int ar = lane & 15;
  const int kslot = ((lane >> 4) & 3) << 4;
  const int nkt = K >> 6;

  f32x4 acc[8][4];
#pragma unroll
  for (int m = 0; m < 8; ++m)
#pragma unroll
    for (int n = 0; n < 4; ++n) acc[m][n] = (f32x4){0.f, 0.f, 0.f, 0.f};

#define CHUNK(b, w_) (lds + (b) * 65536 + (w_) * 16384)
#define STAGE8(Mg, rb, t, kh, c) do { \
  _Pragma("unroll") \
  for (int p_ = 0; p_ < 2; ++p_) { \
    int thr_ = tid + p_ * 512; \
    int row_ = thr_ >> 2; \
    int w_ = ((thr_ & 3) << 4) ^ (((row_ >> 1) & 3) << 4); \
    async_load16((const char*)((Mg) + (size_t)((rb) + row_) * K + (t) * 64 + (kh) * 32) + w_, \
                 (c) + thr_ * 16); \
  } } while (0)
#define FRAG8(c, row) (*(const bf16x8*)((c) + (row) * 64 + (kslot ^ ((((row) >> 1) & 3) << 4))))
#define PHASE8(buf, kh, MH, LOADB, STAGE_STMT, VMC) do { \
  char* ca_ = CHUNK(buf, 1 + 2 * (kh)); \
  if (LOADB) { \
    char* cb_ = CHUNK(buf, 2 * (kh)); \
    _Pragma("unroll") \
    for (int nf_ = 0; nf_ < 4; ++nf_) bfr[nf_] = FRAG8(cb_, wc * 64 + nf_ * 16 + ar); \
  } \
  bf16x8 af_[4]; \
  _Pragma("unroll") \
  for (int mf_ = 0; mf_ < 4; ++mf_) af_[mf_] = FRAG8(ca_, wr * 128 + (MH) * 64 + mf_ * 16 + ar); \
  STAGE_STMT; \
  __builtin_amdgcn_s_barrier(); \
  __builtin_amdgcn_s_setprio(1); \
  _Pragma("unroll") \
  for (int mf_ = 0; mf_ < 4; ++mf_) \
    _Pragma("unroll") \
    for (int nf_ = 0; nf_ < 4; ++nf_) \
      acc[(MH) * 4 + mf_][nf_] = MFMA16(af_[mf_], bfr[nf_], acc[(MH) * 4 + mf_][nf_]); \
  __builtin_amdgcn_s_setprio(0); \
  if (VMC) asm volatile("s_waitcnt vmcnt(6)" ::: "memory"); \
  __builtin_amdgcn_s_barrier(); \
} while (0)

  bf16x8 bfr[4];
  // prologue: 7 chunks (tile0 full + tile1 B.k0,A.k0,B.k1); vmcnt(6) -> tile0 landed
  const int t1p = (nkt > 1) ? 1 : 0;
  STAGE8(Bt, n0, 0, 0, CHUNK(0, 0));
  STAGE8(A,  m0, 0, 0, CHUNK(0, 1));
  STAGE8(Bt, n0, 0, 1, CHUNK(0, 2));
  STAGE8(A,  m0, 0, 1, CHUNK(0, 3));
  STAGE8(Bt, n0, t1p, 0, CHUNK(1, 0));
  STAGE8(A,  m0, t1p, 0, CHUNK(1, 1));
  STAGE8(Bt, n0, t1p, 1, CHUNK(1, 2));
  asm volatile("s_waitcnt vmcnt(6)" ::: "memory");
  __builtin_amdgcn_s_barrier();

  const int niter = nkt >> 1;
  for (int i = 0; i < niter; ++i) {
    const int t1 = (2 * i + 1 < nkt) ? 2 * i + 1 : nkt - 1;
    const int s0 = (2 * i + 2 < nkt) ? 2 * i + 2 : nkt - 1;
    const int s1 = (2 * i + 3 < nkt) ? 2 * i + 3 : nkt - 1;
    // phases 1-4: tile 2i (buf0)
    PHASE8(0, 0, 0, true,  STAGE8(A,  m0, t1, 1, CHUNK(1, 3)), false);
    PHASE8(0, 0, 1, false, STAGE8(Bt, n0, s0, 0, CHUNK(0, 0)), false);
    PHASE8(0, 1, 0, true,  STAGE8(A,  m0, s0, 0, CHUNK(0, 1)), false);
    PHASE8(0, 1, 1, false, STAGE8(Bt, n0, s0, 1, CHUNK(0, 2)), true);
    // phases 5-8: tile 2i+1 (buf1)
    PHASE8(1, 0, 0, true,  STAGE8(A,  m0, s0, 1, CHUNK(0, 3)), false);
    PHASE8(1, 0, 1, false, STAGE8(Bt, n0, s1, 0, CHUNK(1, 0)), false);
    PHASE8(1, 1, 0, true,  STAGE8(A,  m0, s1, 0, CHUNK(1, 1)), false);
    PHASE8(1, 1, 1, false, STAGE8(Bt, n0, s1, 1, CHUNK(1, 2)), true);
  }

#pragma unroll
  for (int mf = 0; mf < 8; ++mf) {
    int row = m0 + wr * 128 + mf * 16 + (lane >> 4) * 4;
#pragma unroll
    for (int nf = 0; nf < 4; ++nf) {
      int col = n0 + wc * 64 + nf * 16 + ar;
      unsigned short* cp = C + (size_t)row * N + col;
#pragma unroll
      for (int j = 0; j < 4; ++j) cp[(size_t)j * N] = f2bf(acc[mf][nf][j]);
    }
  }
#undef CHUNK
#undef STAGE8
#undef FRAG8
#undef PHASE8
}

// ---------------- RoPE apply + head split + V transpose (bf16 qkv in) -------
__global__ __launch_bounds__(256) void rope_kernel(const unsigned short* __restrict__ qkv,
                                                   const float* __restrict__ tc,
                                                   const float* __restrict__ ts,
                                                   unsigned short* __restrict__ qo,
                                                   unsigned short* __restrict__ ko,
                                                   unsigned short* __restrict__ vt) {
  const int S = 2048;
  const int bx = blockIdx.x;
  const int st = bx & 31, bh = bx >> 5;
  const int b = bh >> 4, h = bh & 15;
  const int t = threadIdx.x;
  const int sl = t >> 2, j0 = (t & 3) * 8;
  const int s = st * 64 + sl;
  const unsigned short* row = qkv + (size_t)(b * S + s) * 3072;
  float cv[8], sv[8];
#pragma unroll
  for (int i = 0; i < 8; ++i) {
    cv[i] = tc[s * 32 + j0 + i];
    sv[i] = ts[s * 32 + j0 + i];
  }
  __shared__ unsigned short vtile[64][66];
#pragma unroll
  for (int m = 0; m < 2; ++m) {
    const int col0 = m * 1024 + h * 64;
    const float qscale = (m == 0) ? 0.125f * 1.44269504088896340736f : 1.0f;
    bf16x8 lo8 = *(const bf16x8*)&row[col0 + j0];
    bf16x8 hi8 = *(const bf16x8*)&row[col0 + 32 + j0];
    bf16x8 outlo, outhi;
#pragma unroll
    for (int i = 0; i < 8; ++i) {
      float lo = b2f((unsigned short)lo8[i]), hi = b2f((unsigned short)hi8[i]);
      outlo[i] = (short)f2bf((lo * cv[i] - hi * sv[i]) * qscale);
      outhi[i] = (short)f2bf((hi * cv[i] + lo * sv[i]) * qscale);
    }
    unsigned short* dst = (m == 0 ? qo : ko) + (size_t)(bh * S + s) * 64;
    *(bf16x8*)&dst[j0] = outlo;
    *(bf16x8*)&dst[32 + j0] = outhi;
  }
  {
    const int col0 = 2048 + h * 64;
    bf16x8 v8a = *(const bf16x8*)&row[col0 + j0];
    bf16x8 v8b = *(const bf16x8*)&row[col0 + 32 + j0];
#pragma unroll
    for (int i = 0; i < 8; ++i) {
      vtile[j0 + i][sl] = (unsigned short)v8a[i];
      vtile[j0 + 32 + i][sl] = (unsigned short)v8b[i];
    }
  }
  __syncthreads();
  {
    const int hd = t >> 2, sc0 = (t & 3) * 16;
    unsigned short* dst = vt + ((size_t)bh * 64 + hd) * S + st * 64 + sc0;
    bf16x8 a, bv;
#pragma unroll
    for (int i = 0; i < 8; ++i) {
      a[i] = (short)vtile[hd][sc0 + i];
      bv[i] = (short)vtile[hd][sc0 + 8 + i];
    }
    *(bf16x8*)&dst[0] = a;
    *(bf16x8*)&dst[8] = bv;
  }
}

// ---------------- attention (R17: LDS-staged, balanced mapping) ----------------
__device__ __forceinline__ bf16x8 buildP(const unsigned* w, int tt, int hi) {
  const int base = (tt & 1) * 4 + (tt >> 1) * 8;
  unsigned wA = w[base], wB = w[base + 1], wC = w[base + 2], wD = w[base + 3];
  unsigned s1v = __shfl_xor(hi ? wA : wC, 32);
  unsigned s2v = __shfl_xor(hi ? wB : wD, 32);
  union { unsigned u[4]; bf16x8 v; } pw;
  pw.u[0] = hi ? s1v : wA;
  pw.u[1] = hi ? s2v : wB;
  pw.u[2] = hi ? wC : s1v;
  pw.u[3] = hi ? wD : s2v;
  return pw.v;
}

__device__ __forceinline__ void stage_tiles(const char* kg, const char* vg, int t,
                                            unsigned short* kb, unsigned short* vb,
                                            int wv, int lane) {
  const int lsw = ((lane >> 3) & 7) << 4;
#pragma unroll
  for (int p = 0; p < 2; ++p) {
    const int i = 2 * wv + p;
    const int d = i * 1024 + lane * 16;
    async_load16(kg + (size_t)t * 8192 + (d ^ lsw), (char*)kb + i * 1024);
    const int dim = i * 8 + (lane >> 3);
    const int key2 = (((lane & 7) ^ ((lane >> 3) & 7)) << 4);
    async_load16(vg + (size_t)dim * 4096 + (size_t)t * 128 + key2, (char*)vb + i * 1024);
  }
}

__device__ __forceinline__ void super_lds(const unsigned short* kbuf, const unsigned short* vbuf,
                                          int ql, int hi, int off, const bf16x8 (&qf)[4],
                                          f32x16& a0, f32x16& a1, float& m_run, float& l_run) {
  const char* kb = (const char*)kbuf;
  const char* vb = (const char*)vbuf;
  const int rsw = (ql & 7) << 4;
  bf16x8 k0[4], k1[4];
#pragma unroll
  for (int s = 0; s < 4; ++s) {
    k0[s] = *(const bf16x8*)(kb + (((ql << 7) + (s << 5) + (hi << 4)) ^ rsw));
    k1[s] = *(const bf16x8*)(kb + ((((32 + ql) << 7) + (s << 5) + (hi << 4)) ^ rsw));
  }
  f32x16 s0 = zero16(), s1 = zero16();
  __builtin_amdgcn_s_setprio(1);
#pragma unroll
  for (int s = 0; s < 4; ++s) {
    s0 = MFMA32(k0[s], qf[s], s0);
    s1 = MFMA32(k1[s], qf[s], s1);
  }
  __builtin_amdgcn_s_setprio(0);

  bf16x8 v0[4], v1[4];
#pragma unroll
  for (int tt = 0; tt < 4; ++tt) {
    v0[tt] = *(const bf16x8*)(vb + (((ql << 7) + (tt << 5) + (hi << 4)) ^ rsw));
    v1[tt] = *(const bf16x8*)(vb + ((((32 + ql) << 7) + (tt << 5) + (hi << 4)) ^ rsw));
  }

  if (off < 64) {
#pragma unroll
    for (int r = 0; r < 16; ++r) {
      const int key = (r & 3) + 8 * (r >> 2) + 4 * hi;
      if (key > off + ql) s0[r] = -INFINITY;
      if (key + 32 > off + ql) s1[r] = -INFINITY;
    }
  }

  float p[8];
#pragma unroll
  for (int i = 0; i < 8; ++i)
    p[i] = fmaxf(fmaxf(s0[2 * i], s0[2 * i + 1]), fmaxf(s1[2 * i], s1[2 * i + 1]));
#pragma unroll
  for (int i = 0; i < 4; ++i) p[i] = fmaxf(p[i], p[i + 4]);
  float mx = fmaxf(fmaxf(p[0], p[1]), fmaxf(p[2], p[3]));
  mx = fmaxf(mx, __shfl_xor(mx, 32));
  const bool defer = __all(mx - m_run <= 8.0f) != 0;
  const float mn = defer ? m_run : fmaxf(m_run, mx);
  float r0 = 0.f, r1 = 0.f, r2 = 0.f, r3 = 0.f;
#pragma unroll
  for (int i = 0; i < 4; ++i) {
    float e0 = fexp2(s0[4 * i + 0] - mn); s0[4 * i + 0] = e0; r0 += e0;
    float e1 = fexp2(s0[4 * i + 1] - mn); s0[4 * i + 1] = e1; r1 += e1;
    float e2 = fexp2(s0[4 * i + 2] - mn); s0[4 * i + 2] = e2; r2 += e2;
    float e3 = fexp2(s0[4 * i + 3] - mn); s0[4 * i + 3] = e3; r3 += e3;
  }
#pragma unroll
  for (int i = 0; i < 4; ++i) {
    float e0 = fexp2(s1[4 * i + 0] - mn); s1[4 * i + 0] = e0; r0 += e0;
    float e1 = fexp2(s1[4 * i + 1] - mn); s1[4 * i + 1] = e1; r1 += e1;
    float e2 = fexp2(s1[4 * i + 2] - mn); s1[4 * i + 2] = e2; r2 += e2;
    float e3 = fexp2(s1[4 * i + 3] - mn); s1[4 * i + 3] = e3; r3 += e3;
  }
  const float rs = (r0 + r1) + (r2 + r3);
  if (defer) {
    l_run += rs;
  } else {
    const float scl = fexp2(m_run - mn);
    m_run = mn;
    l_run = l_run * scl + rs;
#pragma unroll
    for (int r = 0; r < 16; ++r) { a0[r] *= scl; a1[r] *= scl; }
  }
  unsigned w[16];
#pragma unroll
  for (int i = 0; i < 8; ++i) {
    w[i] = cvt_pk(s0[2 * i], s0[2 * i + 1]);
    w[8 + i] = cvt_pk(s1[2 * i], s1[2 * i + 1]);
  }
  __builtin_amdgcn_s_setprio(1);
#pragma unroll
  for (int tt = 0; tt < 4; ++tt) {
    bf16x8 pp = buildP(w, tt, hi);
    a0 = MFMA32(v0[tt], pp, a0);
    a1 = MFMA32(v1[tt], pp, a1);
  }
  __builtin_amdgcn_s_setprio(0);
}

__global__ __launch_bounds__(256, 3) void attn_kernel(const unsigned short* __restrict__ Q,
                                                      const unsigned short* __restrict__ Kk,
                                                      const unsigned short* __restrict__ Vt,
                                                      unsigned short* __restrict__ O) {
  const int S = 2048;
  const int tid = threadIdx.x, lane = tid & 63, wv = tid >> 6;
  const int xcd = blockIdx.x & 7;
  const int i = blockIdx.x >> 3;
  const int r = i >> 5, j = i & 31;
  const int jb = j >> 4, jq = j & 15;
  const int bh = xcd * 8 + 2 * r + jb;
  const int qb = (r & 1) ? 15 - jq : jq;
  const int b = bh >> 4, h = bh & 15;
  const int ql = lane & 31, hi = lane >> 5;
  const int qlow = qb * 128 + wv * 32;

  __shared__ unsigned short kbuf[2][4096];
  __shared__ unsigned short vbuf[2][4096];

  const unsigned short* qh = Q + (size_t)bh * S * 64;
  const char* kg = (const char*)(Kk + (size_t)bh * S * 64);
  const char* vg = (const char*)(Vt + (size_t)bh * 64 * S);

  bf16x8 qf[4];
#pragma unroll
  for (int s = 0; s < 4; ++s)
    qf[s] = *(const bf16x8*)&qh[(size_t)(qlow + ql) * 64 + s * 16 + hi * 8];

  f32x16 a0 = zero16(), a1 = zero16();
  float m_run = -INFINITY, l_run = 0.f;

  const int nt = 2 * qb + 2;
  stage_tiles(kg, vg, 0, &kbuf[0][0], &vbuf[0][0], wv, lane);
  __syncthreads();
  int buf = 0;
  for (int t = 0; t < nt; ++t) {
    if (t + 1 < nt)
      stage_tiles(kg, vg, t + 1, &kbuf[buf ^ 1][0], &vbuf[buf ^ 1][0], wv, lane);
    if (t * 64 <= qlow + 31) {
      const int off = qlow - t * 64;
      super_lds(&kbuf[buf][0], &vbuf[buf][0], ql, hi, off, qf, a0, a1, m_run, l_run);
    }
    __syncthreads();
    buf ^= 1;
  }

  l_run += __shfl_xor(l_run, 32);
  const float inv = 1.f / l_run;
  unsigned short* orow = O + (size_t)(b * S + qlow + ql) * 1024 + h * 64;
#pragma unroll
  for (int r2 = 0; r2 < 16; ++r2) {
    int d = (r2 & 3) + 8 * (r2 >> 2) + 4 * hi;
    orow[d] = f2bf(a0[r2] * inv);
    orow[32 + d] = f2bf(a1[r2] * inv);
  }
}

extern "C" void kernel_launch(void* const* d_in, const int* in_sizes, int n_in,
                              void* d_out, int out_size, void* d_ws, size_t ws_size,
                              hipStream_t stream) {
  const float* x = (const float*)d_in[0];
  const float* Wqkv = (const float*)d_in[1];
  const float* Wout = (const float*)d_in[2];
  float* out = (float*)d_out;

  char* ws = (char*)d_ws;
  size_t off = 0;
  auto take = [&](size_t bytes) {
    void* p = ws + off;
    off += (bytes + 255) & ~(size_t)255;
    return p;
  };
  float* tc = (float*)take(2048 * 32 * 4);
  float* tsn = (float*)take(2048 * 32 * 4);
  unsigned short* xbf = (unsigned short*)take((size_t)8192 * 1024 * 2);
  unsigned short* wqkvT = (unsigned short*)take((size_t)3072 * 1024 * 2);
  unsigned short* woutT = (unsigned short*)take((size_t)1024 * 1024 * 2);
  unsigned short* qkvb = (unsigned short*)take((size_t)8192 * 3072 * 2);
  unsigned short* qb_ = (unsigned short*)take((size_t)64 * 2048 * 64 * 2);
  unsigned short* kb_ = (unsigned short*)take((size_t)64 * 2048 * 64 * 2);
  unsigned short* vt = (unsigned short*)take((size_t)64 * 64 * 2048 * 2);
  unsigned short* attn = (unsigned short*)take((size_t)8192 * 1024 * 2);

  rope_table_kernel<<<256, 256, 0, stream>>>(tc, tsn);
  cvt_kernel<<<(2097152 + 255) / 256, 256, 0, stream>>>(x, xbf, 2097152);
  {
    dim3 g(96, 32);
    transpose_cvt<<<g, 256, 0, stream>>>(Wqkv, wqkvT, 1024, 3072);
  }
  {
    dim3 g(32, 32);
    transpose_cvt<<<g, 256, 0, stream>>>(Wout, woutT, 1024, 1024);
  }
  {
    dim3 g(12, 32);   // N/256, M/256
    gemm8p<<<g, 512, 0, stream>>>(xbf, wqkvT, qkvb, 8192, 3072, 1024);
  }
  rope_kernel<<<2048, 256, 0, stream>>>(qkvb, tc, tsn, qb_, kb_, vt);
  attn_kernel<<<1024, 256, 0, stream>>>(qb_, kb_, vt, attn);
  {
    dim3 g(8, 64);
    gemm_bt<false><<<g, 256, 0, stream>>>(attn, woutT, out, 8192, 1024, 1024);
  }
}

// Round 19
// 200.337 us; speedup vs baseline: 4.7178x; 1.0531x over previous
//
#include <hip/hip_runtime.h>
#include <hip/hip_bf16.h>
#include <math.h>

typedef __attribute__((ext_vector_type(8))) short bf16x8;
typedef __attribute__((ext_vector_type(4))) short short4v;
typedef __attribute__((ext_vector_type(4))) float f32x4;
typedef __attribute__((ext_vector_type(16))) float f32x16;

#define MFMA16(a,b,c) __builtin_amdgcn_mfma_f32_16x16x32_bf16(a,b,c,0,0,0)
#define MFMA32(a,b,c) __builtin_amdgcn_mfma_f32_32x32x16_bf16(a,b,c,0,0,0)

__device__ __forceinline__ unsigned short f2bf(float f) {
  union { float f; unsigned u; } v; v.f = f;
  unsigned r = v.u + 0x7FFFu + ((v.u >> 16) & 1u);
  return (unsigned short)(r >> 16);
}
__device__ __forceinline__ float b2f(unsigned short u) {
  union { unsigned u; float f; } v; v.u = (unsigned)u << 16; return v.f;
}

__device__ __forceinline__ unsigned cvt_pk(float lo, float hi) {
  unsigned r;
  asm("v_cvt_pk_bf16_f32 %0, %1, %2" : "=v"(r) : "v"(lo), "v"(hi));
  return r;
}
__device__ __forceinline__ float fexp2(float x) {
  float r;
  asm("v_exp_f32 %0, %1" : "=v"(r) : "v"(x));
  return r;
}

__device__ __forceinline__ void async_load16(const void* g, void* lds) {
  __builtin_amdgcn_global_load_lds(
      (const __attribute__((address_space(1))) unsigned int*)g,
      (__attribute__((address_space(3))) unsigned int*)lds, 16, 0, 0);
}

__device__ __forceinline__ f32x16 zero16() {
  f32x16 z;
#pragma unroll
  for (int i = 0; i < 16; ++i) z[i] = 0.f;
  return z;
}

// ---------------- RoPE table (packed cos/sin) ----------------
__global__ void rope_table_kernel(float2* __restrict__ cs) {
  int i = blockIdx.x * 256 + threadIdx.x;
  if (i >= 2048 * 32) return;
  int s = i >> 5, j = i & 31;
  double invf = pow(10000.0, -(double)(2 * j) / 64.0);
  double ang = (double)s * invf;
  cs[i] = make_float2((float)cos(ang), (float)sin(ang));
}

// ---------------- fp32 -> bf16 elementwise ----------------
__global__ __launch_bounds__(256) void cvt_kernel(const float* __restrict__ in,
                                                  unsigned short* __restrict__ out, int n4) {
  int i = blockIdx.x * 256 + threadIdx.x;
  if (i >= n4) return;
  float4 v = ((const float4*)in)[i];
  short4v o;
  o[0] = (short)f2bf(v.x); o[1] = (short)f2bf(v.y);
  o[2] = (short)f2bf(v.z); o[3] = (short)f2bf(v.w);
  *(short4v*)&out[(size_t)i * 4] = o;
}

// ---------------- fp32 [R][C] -> bf16 [C][R] transpose ----------------
__global__ __launch_bounds__(256) void transpose_cvt(const float* __restrict__ in,
                                                     unsigned short* __restrict__ out,
                                                     int R, int C) {
  __shared__ float tile[32][33];
  const int bx = blockIdx.x * 32, by = blockIdx.y * 32;
  const int tx = threadIdx.x & 31, ty0 = threadIdx.x >> 5;
#pragma unroll
  for (int p = 0; p < 4; ++p) {
    int r = ty0 + p * 8;
    tile[r][tx] = in[(size_t)(by + r) * C + bx + tx];
  }
  __syncthreads();
#pragma unroll
  for (int p = 0; p < 4; ++p) {
    int r = ty0 + p * 8;
    out[(size_t)(bx + r) * R + by + tx] = f2bf(tile[tx][r]);
  }
}

// ---------------- GEMM m97 (for GEMM2), fp32 out ----------
__global__ __launch_bounds__(256) void gemm_bt(const unsigned short* __restrict__ A,
                                               const unsigned short* __restrict__ Bt,
                                               float* __restrict__ C,
                                               int M, int N, int K) {
  __shared__ unsigned short As[128 * 32];
  __shared__ unsigned short Bs[128 * 32];
  const int t = threadIdx.x, lane = t & 63, wv = t >> 6;
  const int bn = blockIdx.x, bm = blockIdx.y;
  const int m0 = bm * 128, n0 = bn * 128;
  f32x4 acc[4][4];
#pragma unroll
  for (int m = 0; m < 4; ++m)
#pragma unroll
    for (int n = 0; n < 4; ++n) acc[m][n] = (f32x4){0.f, 0.f, 0.f, 0.f};
  const int wr = (wv >> 1) * 64, wc = (wv & 1) * 64;
  const int ar = lane & 15, ak = (lane >> 4) * 8;
  const int srow = lane >> 2, skc = (lane & 3) * 8;
  const int nkt = K >> 5;
  for (int kt = 0; kt < nkt; ++kt) {
    const unsigned short* Ag = A + (size_t)m0 * K + kt * 32;
    const unsigned short* Bg = Bt + (size_t)n0 * K + kt * 32;
#pragma unroll
    for (int p = 0; p < 2; ++p) {
      int c = wv * 2 + p;
      async_load16(Ag + (size_t)(c * 16 + srow) * K + skc, &As[c * 512]);
      async_load16(Bg + (size_t)(c * 16 + srow) * K + skc, &Bs[c * 512]);
    }
    __syncthreads();
    bf16x8 af[4], bfr[4];
#pragma unroll
    for (int m = 0; m < 4; ++m) af[m] = *(const bf16x8*)&As[(wr + m * 16 + ar) * 32 + ak];
#pragma unroll
    for (int n = 0; n < 4; ++n) bfr[n] = *(const bf16x8*)&Bs[(wc + n * 16 + ar) * 32 + ak];
#pragma unroll
    for (int m = 0; m < 4; ++m)
#pragma unroll
      for (int n = 0; n < 4; ++n) acc[m][n] = MFMA16(af[m], bfr[n], acc[m][n]);
    __syncthreads();
  }
#pragma unroll
  for (int m = 0; m < 4; ++m) {
    int row = m0 + wr + m * 16 + (lane >> 4) * 4;
#pragma unroll
    for (int n = 0; n < 4; ++n) {
      int col = n0 + wc + n * 16 + ar;
      float* cp = C + (size_t)row * N + col;
#pragma unroll
      for (int j = 0; j < 4; ++j) cp[(size_t)j * N] = acc[m][n][j];
    }
  }
}

// ---------------- GEMM 256x256 8-phase + fused RoPE/head-split/V-T epilogue ----
// 512 threads = 8 waves (2M x 4N), per-wave C = 128x64 = acc[8][4].
// LDS 128KB: 2 bufs x {B.k0, A.k0, B.k1, A.k1} 16KB chunks.
// Epilogue: region = n0>>10 (block-uniform); RoPE pair (j,j+32) = (nf,nf+2)
// in-thread; head h = ((n0&1023)>>6)+wc wave-uniform; V transposed to
// vt[bh][64][S] with aligned 8B stores (4 consecutive s per acc column).
__global__ __launch_bounds__(512, 2) void gemm8p(const unsigned short* __restrict__ A,
                                                 const unsigned short* __restrict__ Bt,
                                                 unsigned short* __restrict__ qo,
                                                 unsigned short* __restrict__ ko,
                                                 unsigned short* __restrict__ vt,
                                                 const float2* __restrict__ cs,
                                                 int M, int N, int K) {
  __shared__ char lds[131072];
  const int tid = threadIdx.x, lane = tid & 63, wv = tid >> 6;
  const int wr = wv >> 2, wc = wv & 3;
  const int m0 = blockIdx.y * 256, n0 = blockIdx.x * 256;
  const int ar = lane & 15;
  const int kslot = ((lane >> 4) & 3) << 4;
  const int nkt = K >> 6;

  f32x4 acc[8][4];
#pragma unroll
  for (int m = 0; m < 8; ++m)
#pragma unroll
    for (int n = 0; n < 4; ++n) acc[m][n] = (f32x4){0.f, 0.f, 0.f, 0.f};

#define CHUNK(b, w_) (lds + (b) * 65536 + (w_) * 16384)
#define STAGE8(Mg, rb, t, kh, c) do { \
  _Pragma("unroll") \
  for (int p_ = 0; p_ < 2; ++p_) { \
    int thr_ = tid + p_ * 512; \
    int row_ = thr_ >> 2; \
    int w_ = ((thr_ & 3) << 4) ^ (((row_ >> 1) & 3) << 4); \
    async_load16((const char*)((Mg) + (size_t)((rb) + row_) * K + (t) * 64 + (kh) * 32) + w_, \
                 (c) + thr_ * 16); \
  } } while (0)
#define FRAG8(c, row) (*(const bf16x8*)((c) + (row) * 64 + (kslot ^ ((((row) >> 1) & 3) << 4))))
#define PHASE8(buf, kh, MH, LOADB, STAGE_STMT, VMC) do { \
  char* ca_ = CHUNK(buf, 1 + 2 * (kh)); \
  if (LOADB) { \
    char* cb_ = CHUNK(buf, 2 * (kh)); \
    _Pragma("unroll") \
    for (int nf_ = 0; nf_ < 4; ++nf_) bfr[nf_] = FRAG8(cb_, wc * 64 + nf_ * 16 + ar); \
  } \
  bf16x8 af_[4]; \
  _Pragma("unroll") \
  for (int mf_ = 0; mf_ < 4; ++mf_) af_[mf_] = FRAG8(ca_, wr * 128 + (MH) * 64 + mf_ * 16 + ar); \
  STAGE_STMT; \
  __builtin_amdgcn_s_barrier(); \
  __builtin_amdgcn_s_setprio(1); \
  _Pragma("unroll") \
  for (int mf_ = 0; mf_ < 4; ++mf_) \
    _Pragma("unroll") \
    for (int nf_ = 0; nf_ < 4; ++nf_) \
      acc[(MH) * 4 + mf_][nf_] = MFMA16(af_[mf_], bfr[nf_], acc[(MH) * 4 + mf_][nf_]); \
  __builtin_amdgcn_s_setprio(0); \
  if (VMC) asm volatile("s_waitcnt vmcnt(6)" ::: "memory"); \
  __builtin_amdgcn_s_barrier(); \
} while (0)

  bf16x8 bfr[4];
  const int t1p = (nkt > 1) ? 1 : 0;
  STAGE8(Bt, n0, 0, 0, CHUNK(0, 0));
  STAGE8(A,  m0, 0, 0, CHUNK(0, 1));
  STAGE8(Bt, n0, 0, 1, CHUNK(0, 2));
  STAGE8(A,  m0, 0, 1, CHUNK(0, 3));
  STAGE8(Bt, n0, t1p, 0, CHUNK(1, 0));
  STAGE8(A,  m0, t1p, 0, CHUNK(1, 1));
  STAGE8(Bt, n0, t1p, 1, CHUNK(1, 2));
  asm volatile("s_waitcnt vmcnt(6)" ::: "memory");
  __builtin_amdgcn_s_barrier();

  const int niter = nkt >> 1;
  for (int i = 0; i < niter; ++i) {
    const int t1 = (2 * i + 1 < nkt) ? 2 * i + 1 : nkt - 1;
    const int s0 = (2 * i + 2 < nkt) ? 2 * i + 2 : nkt - 1;
    const int s1 = (2 * i + 3 < nkt) ? 2 * i + 3 : nkt - 1;
    PHASE8(0, 0, 0, true,  STAGE8(A,  m0, t1, 1, CHUNK(1, 3)), false);
    PHASE8(0, 0, 1, false, STAGE8(Bt, n0, s0, 0, CHUNK(0, 0)), false);
    PHASE8(0, 1, 0, true,  STAGE8(A,  m0, s0, 0, CHUNK(0, 1)), false);
    PHASE8(0, 1, 1, false, STAGE8(Bt, n0, s0, 1, CHUNK(0, 2)), true);
    PHASE8(1, 0, 0, true,  STAGE8(A,  m0, s0, 1, CHUNK(0, 3)), false);
    PHASE8(1, 0, 1, false, STAGE8(Bt, n0, s1, 0, CHUNK(1, 0)), false);
    PHASE8(1, 1, 0, true,  STAGE8(A,  m0, s1, 0, CHUNK(1, 1)), false);
    PHASE8(1, 1, 1, false, STAGE8(Bt, n0, s1, 1, CHUNK(1, 2)), true);
  }

  // ---- fused epilogue: RoPE(q,k) + head split + V transpose ----
  const int reg = n0 >> 10;                   // 0=q, 1=k, 2=v (block-uniform)
  const int h = ((n0 & 1023) >> 6) + wc;      // head (wave-uniform)
  if (reg < 2) {
    const float qsc = (reg == 0) ? 0.125f * 1.44269504088896340736f : 1.0f;
    unsigned short* dst = (reg == 0) ? qo : ko;
#pragma unroll
    for (int mf = 0; mf < 8; ++mf) {
#pragma unroll
      for (int j = 0; j < 4; ++j) {
        const int row = m0 + wr * 128 + mf * 16 + (lane >> 4) * 4 + j;
        const int b = row >> 11, s = row & 2047;
        unsigned short* o = dst + ((size_t)(b * 16 + h) * 2048 + s) * 64;
#pragma unroll
        for (int nf = 0; nf < 2; ++nf) {
          const int jj = nf * 16 + ar;
          const float2 c2 = cs[s * 32 + jj];
          const float lo = acc[mf][nf][j], hv = acc[mf][nf + 2][j];
          o[jj] = f2bf((lo * c2.x - hv * c2.y) * qsc);
          o[jj + 32] = f2bf((hv * c2.x + lo * c2.y) * qsc);
        }
      }
    }
  } else {
#pragma unroll
    for (int mf = 0; mf < 8; ++mf) {
      const int row0 = m0 + wr * 128 + mf * 16 + (lane >> 4) * 4;
      const int b = row0 >> 11, s0r = row0 & 2047;
#pragma unroll
      for (int nf = 0; nf < 4; ++nf) {
        const int d = nf * 16 + ar;
        unsigned short* o = vt + ((size_t)((b * 16 + h) * 64 + d)) * 2048 + s0r;
        short4v pk;
#pragma unroll
        for (int j = 0; j < 4; ++j) pk[j] = (short)f2bf(acc[mf][nf][j]);
        *(short4v*)o = pk;
      }
    }
  }
#undef CHUNK
#undef STAGE8
#undef FRAG8
#undef PHASE8
}

// ---------------- attention (R17: LDS-staged, balanced mapping) ----------------
__device__ __forceinline__ bf16x8 buildP(const unsigned* w, int tt, int hi) {
  const int base = (tt & 1) * 4 + (tt >> 1) * 8;
  unsigned wA = w[base], wB = w[base + 1], wC = w[base + 2], wD = w[base + 3];
  unsigned s1v = __shfl_xor(hi ? wA : wC, 32);
  unsigned s2v = __shfl_xor(hi ? wB : wD, 32);
  union { unsigned u[4]; bf16x8 v; } pw;
  pw.u[0] = hi ? s1v : wA;
  pw.u[1] = hi ? s2v : wB;
  pw.u[2] = hi ? wC : s1v;
  pw.u[3] = hi ? wD : s2v;
  return pw.v;
}

__device__ __forceinline__ void stage_tiles(const char* kg, const char* vg, int t,
                                            unsigned short* kb, unsigned short* vb,
                                            int wv, int lane) {
  const int lsw = ((lane >> 3) & 7) << 4;
#pragma unroll
  for (int p = 0; p < 2; ++p) {
    const int i = 2 * wv + p;
    const int d = i * 1024 + lane * 16;
    async_load16(kg + (size_t)t * 8192 + (d ^ lsw), (char*)kb + i * 1024);
    const int dim = i * 8 + (lane >> 3);
    const int key2 = (((lane & 7) ^ ((lane >> 3) & 7)) << 4);
    async_load16(vg + (size_t)dim * 4096 + (size_t)t * 128 + key2, (char*)vb + i * 1024);
  }
}

__device__ __forceinline__ void super_lds(const unsigned short* kbuf, const unsigned short* vbuf,
                                          int ql, int hi, int off, const bf16x8 (&qf)[4],
                                          f32x16& a0, f32x16& a1, float& m_run, float& l_run) {
  const char* kb = (const char*)kbuf;
  const char* vb = (const char*)vbuf;
  const int rsw = (ql & 7) << 4;
  bf16x8 k0[4], k1[4];
#pragma unroll
  for (int s = 0; s < 4; ++s) {
    k0[s] = *(const bf16x8*)(kb + (((ql << 7) + (s << 5) + (hi << 4)) ^ rsw));
    k1[s] = *(const bf16x8*)(kb + ((((32 + ql) << 7) + (s << 5) + (hi << 4)) ^ rsw));
  }
  f32x16 s0 = zero16(), s1 = zero16();
  __builtin_amdgcn_s_setprio(1);
#pragma unroll
  for (int s = 0; s < 4; ++s) {
    s0 = MFMA32(k0[s], qf[s], s0);
    s1 = MFMA32(k1[s], qf[s], s1);
  }
  __builtin_amdgcn_s_setprio(0);

  bf16x8 v0[4], v1[4];
#pragma unroll
  for (int tt = 0; tt < 4; ++tt) {
    v0[tt] = *(const bf16x8*)(vb + (((ql << 7) + (tt << 5) + (hi << 4)) ^ rsw));
    v1[tt] = *(const bf16x8*)(vb + ((((32 + ql) << 7) + (tt << 5) + (hi << 4)) ^ rsw));
  }

  if (off < 64) {
#pragma unroll
    for (int r = 0; r < 16; ++r) {
      const int key = (r & 3) + 8 * (r >> 2) + 4 * hi;
      if (key > off + ql) s0[r] = -INFINITY;
      if (key + 32 > off + ql) s1[r] = -INFINITY;
    }
  }

  float p[8];
#pragma unroll
  for (int i = 0; i < 8; ++i)
    p[i] = fmaxf(fmaxf(s0[2 * i], s0[2 * i + 1]), fmaxf(s1[2 * i], s1[2 * i + 1]));
#pragma unroll
  for (int i = 0; i < 4; ++i) p[i] = fmaxf(p[i], p[i + 4]);
  float mx = fmaxf(fmaxf(p[0], p[1]), fmaxf(p[2], p[3]));
  mx = fmaxf(mx, __shfl_xor(mx, 32));
  const bool defer = __all(mx - m_run <= 8.0f) != 0;
  const float mn = defer ? m_run : fmaxf(m_run, mx);
  float r0 = 0.f, r1 = 0.f, r2 = 0.f, r3 = 0.f;
#pragma unroll
  for (int i = 0; i < 4; ++i) {
    float e0 = fexp2(s0[4 * i + 0] - mn); s0[4 * i + 0] = e0; r0 += e0;
    float e1 = fexp2(s0[4 * i + 1] - mn); s0[4 * i + 1] = e1; r1 += e1;
    float e2 = fexp2(s0[4 * i + 2] - mn); s0[4 * i + 2] = e2; r2 += e2;
    float e3 = fexp2(s0[4 * i + 3] - mn); s0[4 * i + 3] = e3; r3 += e3;
  }
#pragma unroll
  for (int i = 0; i < 4; ++i) {
    float e0 = fexp2(s1[4 * i + 0] - mn); s1[4 * i + 0] = e0; r0 += e0;
    float e1 = fexp2(s1[4 * i + 1] - mn); s1[4 * i + 1] = e1; r1 += e1;
    float e2 = fexp2(s1[4 * i + 2] - mn); s1[4 * i + 2] = e2; r2 += e2;
    float e3 = fexp2(s1[4 * i + 3] - mn); s1[4 * i + 3] = e3; r3 += e3;
  }
  const float rs = (r0 + r1) + (r2 + r3);
  if (defer) {
    l_run += rs;
  } else {
    const float scl = fexp2(m_run - mn);
    m_run = mn;
    l_run = l_run * scl + rs;
#pragma unroll
    for (int r = 0; r < 16; ++r) { a0[r] *= scl; a1[r] *= scl; }
  }
  unsigned w[16];
#pragma unroll
  for (int i = 0; i < 8; ++i) {
    w[i] = cvt_pk(s0[2 * i], s0[2 * i + 1]);
    w[8 + i] = cvt_pk(s1[2 * i], s1[2 * i + 1]);
  }
  __builtin_amdgcn_s_setprio(1);
#pragma unroll
  for (int tt = 0; tt < 4; ++tt) {
    bf16x8 pp = buildP(w, tt, hi);
    a0 = MFMA32(v0[tt], pp, a0);
    a1 = MFMA32(v1[tt], pp, a1);
  }
  __builtin_amdgcn_s_setprio(0);
}

__global__ __launch_bounds__(256, 3) void attn_kernel(const unsigned short* __restrict__ Q,
                                                      const unsigned short* __restrict__ Kk,
                                                      const unsigned short* __restrict__ Vt,
                                                      unsigned short* __restrict__ O) {
  const int S = 2048;
  const int tid = threadIdx.x, lane = tid & 63, wv = tid >> 6;
  const int xcd = blockIdx.x & 7;
  const int i = blockIdx.x >> 3;
  const int r = i >> 5, j = i & 31;
  const int jb = j >> 4, jq = j & 15;
  const int bh = xcd * 8 + 2 * r + jb;
  const int qb = (r & 1) ? 15 - jq : jq;
  const int b = bh >> 4, h = bh & 15;
  const int ql = lane & 31, hi = lane >> 5;
  const int qlow = qb * 128 + wv * 32;

  __shared__ unsigned short kbuf[2][4096];
  __shared__ unsigned short vbuf[2][4096];

  const unsigned short* qh = Q + (size_t)bh * S * 64;
  const char* kg = (const char*)(Kk + (size_t)bh * S * 64);
  const char* vg = (const char*)(Vt + (size_t)bh * 64 * S);

  bf16x8 qf[4];
#pragma unroll
  for (int s = 0; s < 4; ++s)
    qf[s] = *(const bf16x8*)&qh[(size_t)(qlow + ql) * 64 + s * 16 + hi * 8];

  f32x16 a0 = zero16(), a1 = zero16();
  float m_run = -INFINITY, l_run = 0.f;

  const int nt = 2 * qb + 2;
  stage_tiles(kg, vg, 0, &kbuf[0][0], &vbuf[0][0], wv, lane);
  __syncthreads();
  int buf = 0;
  for (int t = 0; t < nt; ++t) {
    if (t + 1 < nt)
      stage_tiles(kg, vg, t + 1, &kbuf[buf ^ 1][0], &vbuf[buf ^ 1][0], wv, lane);
    if (t * 64 <= qlow + 31) {
      const int off = qlow - t * 64;
      super_lds(&kbuf[buf][0], &vbuf[buf][0], ql, hi, off, qf, a0, a1, m_run, l_run);
    }
    __syncthreads();
    buf ^= 1;
  }

  l_run += __shfl_xor(l_run, 32);
  const float inv = 1.f / l_run;
  unsigned short* orow = O + (size_t)(b * S + qlow + ql) * 1024 + h * 64;
#pragma unroll
  for (int r2 = 0; r2 < 16; ++r2) {
    int d = (r2 & 3) + 8 * (r2 >> 2) + 4 * hi;
    orow[d] = f2bf(a0[r2] * inv);
    orow[32 + d] = f2bf(a1[r2] * inv);
  }
}

extern "C" void kernel_launch(void* const* d_in, const int* in_sizes, int n_in,
                              void* d_out, int out_size, void* d_ws, size_t ws_size,
                              hipStream_t stream) {
  const float* x = (const float*)d_in[0];
  const float* Wqkv = (const float*)d_in[1];
  const float* Wout = (const float*)d_in[2];
  float* out = (float*)d_out;

  char* ws = (char*)d_ws;
  size_t off = 0;
  auto take = [&](size_t bytes) {
    void* p = ws + off;
    off += (bytes + 255) & ~(size_t)255;
    return p;
  };
  float2* cs = (float2*)take((size_t)2048 * 32 * 8);
  unsigned short* xbf = (unsigned short*)take((size_t)8192 * 1024 * 2);
  unsigned short* wqkvT = (unsigned short*)take((size_t)3072 * 1024 * 2);
  unsigned short* woutT = (unsigned short*)take((size_t)1024 * 1024 * 2);
  unsigned short* qb_ = (unsigned short*)take((size_t)64 * 2048 * 64 * 2);
  unsigned short* kb_ = (unsigned short*)take((size_t)64 * 2048 * 64 * 2);
  unsigned short* vt = (unsigned short*)take((size_t)64 * 64 * 2048 * 2);
  unsigned short* attn = (unsigned short*)take((size_t)8192 * 1024 * 2);

  rope_table_kernel<<<256, 256, 0, stream>>>(cs);
  cvt_kernel<<<(2097152 + 255) / 256, 256, 0, stream>>>(x, xbf, 2097152);
  {
    dim3 g(96, 32);
    transpose_cvt<<<g, 256, 0, stream>>>(Wqkv, wqkvT, 1024, 3072);
  }
  {
    dim3 g(32, 32);
    transpose_cvt<<<g, 256, 0, stream>>>(Wout, woutT, 1024, 1024);
  }
  {
    dim3 g(12, 32);   // N/256, M/256
    gemm8p<<<g, 512, 0, stream>>>(xbf, wqkvT, qb_, kb_, vt, cs, 8192, 3072, 1024);
  }
  attn_kernel<<<1024, 256, 0, stream>>>(qb_, kb_, vt, attn);
  {
    dim3 g(8, 64);
    gemm_bt<<<g, 256, 0, stream>>>(attn, woutT, out, 8192, 1024, 1024);
  }
}

// Round 20
// 200.173 us; speedup vs baseline: 4.7216x; 1.0008x over previous
//
#include <hip/hip_runtime.h>
#include <hip/hip_bf16.h>
#include <math.h>

typedef __attribute__((ext_vector_type(8))) short bf16x8;
typedef __attribute__((ext_vector_type(4))) short short4v;
typedef __attribute__((ext_vector_type(4))) float f32x4;
typedef __attribute__((ext_vector_type(16))) float f32x16;

#define MFMA16(a,b,c) __builtin_amdgcn_mfma_f32_16x16x32_bf16(a,b,c,0,0,0)
#define MFMA32(a,b,c) __builtin_amdgcn_mfma_f32_32x32x16_bf16(a,b,c,0,0,0)

__device__ __forceinline__ unsigned short f2bf(float f) {
  union { float f; unsigned u; } v; v.f = f;
  unsigned r = v.u + 0x7FFFu + ((v.u >> 16) & 1u);
  return (unsigned short)(r >> 16);
}
__device__ __forceinline__ float b2f(unsigned short u) {
  union { unsigned u; float f; } v; v.u = (unsigned)u << 16; return v.f;
}

__device__ __forceinline__ unsigned cvt_pk(float lo, float hi) {
  unsigned r;
  asm("v_cvt_pk_bf16_f32 %0, %1, %2" : "=v"(r) : "v"(lo), "v"(hi));
  return r;
}
__device__ __forceinline__ float fexp2(float x) {
  float r;
  asm("v_exp_f32 %0, %1" : "=v"(r) : "v"(x));
  return r;
}

__device__ __forceinline__ void async_load16(const void* g, void* lds) {
  __builtin_amdgcn_global_load_lds(
      (const __attribute__((address_space(1))) unsigned int*)g,
      (__attribute__((address_space(3))) unsigned int*)lds, 16, 0, 0);
}

__device__ __forceinline__ f32x16 zero16() {
  f32x16 z;
#pragma unroll
  for (int i = 0; i < 16; ++i) z[i] = 0.f;
  return z;
}

// ---------------- RoPE table (packed cos/sin) ----------------
__global__ void rope_table_kernel(float2* __restrict__ cs) {
  int i = blockIdx.x * 256 + threadIdx.x;
  if (i >= 2048 * 32) return;
  int s = i >> 5, j = i & 31;
  double invf = pow(10000.0, -(double)(2 * j) / 64.0);
  double ang = (double)s * invf;
  cs[i] = make_float2((float)cos(ang), (float)sin(ang));
}

// ---------------- fp32 -> bf16 elementwise ----------------
__global__ __launch_bounds__(256) void cvt_kernel(const float* __restrict__ in,
                                                  unsigned short* __restrict__ out, int n4) {
  int i = blockIdx.x * 256 + threadIdx.x;
  if (i >= n4) return;
  float4 v = ((const float4*)in)[i];
  short4v o;
  o[0] = (short)f2bf(v.x); o[1] = (short)f2bf(v.y);
  o[2] = (short)f2bf(v.z); o[3] = (short)f2bf(v.w);
  *(short4v*)&out[(size_t)i * 4] = o;
}

// ---------------- fp32 [R][C] -> bf16 [C][R] transpose ----------------
__global__ __launch_bounds__(256) void transpose_cvt(const float* __restrict__ in,
                                                     unsigned short* __restrict__ out,
                                                     int R, int C) {
  __shared__ float tile[32][33];
  const int bx = blockIdx.x * 32, by = blockIdx.y * 32;
  const int tx = threadIdx.x & 31, ty0 = threadIdx.x >> 5;
#pragma unroll
  for (int p = 0; p < 4; ++p) {
    int r = ty0 + p * 8;
    tile[r][tx] = in[(size_t)(by + r) * C + bx + tx];
  }
  __syncthreads();
#pragma unroll
  for (int p = 0; p < 4; ++p) {
    int r = ty0 + p * 8;
    out[(size_t)(bx + r) * R + by + tx] = f2bf(tile[tx][r]);
  }
}

// ---------------- GEMM m97 (for GEMM2), fp32 out ----------
__global__ __launch_bounds__(256) void gemm_bt(const unsigned short* __restrict__ A,
                                               const unsigned short* __restrict__ Bt,
                                               float* __restrict__ C,
                                               int M, int N, int K) {
  __shared__ unsigned short As[128 * 32];
  __shared__ unsigned short Bs[128 * 32];
  const int t = threadIdx.x, lane = t & 63, wv = t >> 6;
  const int bn = blockIdx.x, bm = blockIdx.y;
  const int m0 = bm * 128, n0 = bn * 128;
  f32x4 acc[4][4];
#pragma unroll
  for (int m = 0; m < 4; ++m)
#pragma unroll
    for (int n = 0; n < 4; ++n) acc[m][n] = (f32x4){0.f, 0.f, 0.f, 0.f};
  const int wr = (wv >> 1) * 64, wc = (wv & 1) * 64;
  const int ar = lane & 15, ak = (lane >> 4) * 8;
  const int srow = lane >> 2, skc = (lane & 3) * 8;
  const int nkt = K >> 5;
  for (int kt = 0; kt < nkt; ++kt) {
    const unsigned short* Ag = A + (size_t)m0 * K + kt * 32;
    const unsigned short* Bg = Bt + (size_t)n0 * K + kt * 32;
#pragma unroll
    for (int p = 0; p < 2; ++p) {
      int c = wv * 2 + p;
      async_load16(Ag + (size_t)(c * 16 + srow) * K + skc, &As[c * 512]);
      async_load16(Bg + (size_t)(c * 16 + srow) * K + skc, &Bs[c * 512]);
    }
    __syncthreads();
    bf16x8 af[4], bfr[4];
#pragma unroll
    for (int m = 0; m < 4; ++m) af[m] = *(const bf16x8*)&As[(wr + m * 16 + ar) * 32 + ak];
#pragma unroll
    for (int n = 0; n < 4; ++n) bfr[n] = *(const bf16x8*)&Bs[(wc + n * 16 + ar) * 32 + ak];
#pragma unroll
    for (int m = 0; m < 4; ++m)
#pragma unroll
      for (int n = 0; n < 4; ++n) acc[m][n] = MFMA16(af[m], bfr[n], acc[m][n]);
    __syncthreads();
  }
#pragma unroll
  for (int m = 0; m < 4; ++m) {
    int row = m0 + wr + m * 16 + (lane >> 4) * 4;
#pragma unroll
    for (int n = 0; n < 4; ++n) {
      int col = n0 + wc + n * 16 + ar;
      float* cp = C + (size_t)row * N + col;
#pragma unroll
      for (int j = 0; j < 4; ++j) cp[(size_t)j * N] = acc[m][n][j];
    }
  }
}

// ---------------- GEMM 256x256 8-phase + fused RoPE/head-split/V-T epilogue ----
__global__ __launch_bounds__(512, 2) void gemm8p(const unsigned short* __restrict__ A,
                                                 const unsigned short* __restrict__ Bt,
                                                 unsigned short* __restrict__ qo,
                                                 unsigned short* __restrict__ ko,
                                                 unsigned short* __restrict__ vt,
                                                 const float2* __restrict__ cs,
                                                 int M, int N, int K) {
  __shared__ char lds[131072];
  const int tid = threadIdx.x, lane = tid & 63, wv = tid >> 6;
  const int wr = wv >> 2, wc = wv & 3;
  const int m0 = blockIdx.y * 256, n0 = blockIdx.x * 256;
  const int ar = lane & 15;
  const int kslot = ((lane >> 4) & 3) << 4;
  const int nkt = K >> 6;

  f32x4 acc[8][4];
#pragma unroll
  for (int m = 0; m < 8; ++m)
#pragma unroll
    for (int n = 0; n < 4; ++n) acc[m][n] = (f32x4){0.f, 0.f, 0.f, 0.f};

#define CHUNK(b, w_) (lds + (b) * 65536 + (w_) * 16384)
#define STAGE8(Mg, rb, t, kh, c) do { \
  _Pragma("unroll") \
  for (int p_ = 0; p_ < 2; ++p_) { \
    int thr_ = tid + p_ * 512; \
    int row_ = thr_ >> 2; \
    int w_ = ((thr_ & 3) << 4) ^ (((row_ >> 1) & 3) << 4); \
    async_load16((const char*)((Mg) + (size_t)((rb) + row_) * K + (t) * 64 + (kh) * 32) + w_, \
                 (c) + thr_ * 16); \
  } } while (0)
#define FRAG8(c, row) (*(const bf16x8*)((c) + (row) * 64 + (kslot ^ ((((row) >> 1) & 3) << 4))))
#define PHASE8(buf, kh, MH, LOADB, STAGE_STMT, VMC) do { \
  char* ca_ = CHUNK(buf, 1 + 2 * (kh)); \
  if (LOADB) { \
    char* cb_ = CHUNK(buf, 2 * (kh)); \
    _Pragma("unroll") \
    for (int nf_ = 0; nf_ < 4; ++nf_) bfr[nf_] = FRAG8(cb_, wc * 64 + nf_ * 16 + ar); \
  } \
  bf16x8 af_[4]; \
  _Pragma("unroll") \
  for (int mf_ = 0; mf_ < 4; ++mf_) af_[mf_] = FRAG8(ca_, wr * 128 + (MH) * 64 + mf_ * 16 + ar); \
  STAGE_STMT; \
  __builtin_amdgcn_s_barrier(); \
  __builtin_amdgcn_s_setprio(1); \
  _Pragma("unroll") \
  for (int mf_ = 0; mf_ < 4; ++mf_) \
    _Pragma("unroll") \
    for (int nf_ = 0; nf_ < 4; ++nf_) \
      acc[(MH) * 4 + mf_][nf_] = MFMA16(af_[mf_], bfr[nf_], acc[(MH) * 4 + mf_][nf_]); \
  __builtin_amdgcn_s_setprio(0); \
  if (VMC) asm volatile("s_waitcnt vmcnt(6)" ::: "memory"); \
  __builtin_amdgcn_s_barrier(); \
} while (0)

  bf16x8 bfr[4];
  const int t1p = (nkt > 1) ? 1 : 0;
  STAGE8(Bt, n0, 0, 0, CHUNK(0, 0));
  STAGE8(A,  m0, 0, 0, CHUNK(0, 1));
  STAGE8(Bt, n0, 0, 1, CHUNK(0, 2));
  STAGE8(A,  m0, 0, 1, CHUNK(0, 3));
  STAGE8(Bt, n0, t1p, 0, CHUNK(1, 0));
  STAGE8(A,  m0, t1p, 0, CHUNK(1, 1));
  STAGE8(Bt, n0, t1p, 1, CHUNK(1, 2));
  asm volatile("s_waitcnt vmcnt(6)" ::: "memory");
  __builtin_amdgcn_s_barrier();

  const int niter = nkt >> 1;
  for (int i = 0; i < niter; ++i) {
    const int t1 = (2 * i + 1 < nkt) ? 2 * i + 1 : nkt - 1;
    const int s0 = (2 * i + 2 < nkt) ? 2 * i + 2 : nkt - 1;
    const int s1 = (2 * i + 3 < nkt) ? 2 * i + 3 : nkt - 1;
    PHASE8(0, 0, 0, true,  STAGE8(A,  m0, t1, 1, CHUNK(1, 3)), false);
    PHASE8(0, 0, 1, false, STAGE8(Bt, n0, s0, 0, CHUNK(0, 0)), false);
    PHASE8(0, 1, 0, true,  STAGE8(A,  m0, s0, 0, CHUNK(0, 1)), false);
    PHASE8(0, 1, 1, false, STAGE8(Bt, n0, s0, 1, CHUNK(0, 2)), true);
    PHASE8(1, 0, 0, true,  STAGE8(A,  m0, s0, 1, CHUNK(0, 3)), false);
    PHASE8(1, 0, 1, false, STAGE8(Bt, n0, s1, 0, CHUNK(1, 0)), false);
    PHASE8(1, 1, 0, true,  STAGE8(A,  m0, s1, 0, CHUNK(1, 1)), false);
    PHASE8(1, 1, 1, false, STAGE8(Bt, n0, s1, 1, CHUNK(1, 2)), true);
  }

  // ---- fused epilogue: RoPE(q,k) + head split + V transpose ----
  const int reg = n0 >> 10;                   // 0=q, 1=k, 2=v (block-uniform)
  const int h = ((n0 & 1023) >> 6) + wc;      // head (wave-uniform)
  if (reg < 2) {
    const float qsc = (reg == 0) ? 0.125f * 1.44269504088896340736f : 1.0f;
    unsigned short* dst = (reg == 0) ? qo : ko;
#pragma unroll
    for (int mf = 0; mf < 8; ++mf) {
#pragma unroll
      for (int j = 0; j < 4; ++j) {
        const int row = m0 + wr * 128 + mf * 16 + (lane >> 4) * 4 + j;
        const int b = row >> 11, s = row & 2047;
        unsigned short* o = dst + ((size_t)(b * 16 + h) * 2048 + s) * 64;
#pragma unroll
        for (int nf = 0; nf < 2; ++nf) {
          const int jj = nf * 16 + ar;
          const float2 c2 = cs[s * 32 + jj];
          const float lo = acc[mf][nf][j], hv = acc[mf][nf + 2][j];
          o[jj] = f2bf((lo * c2.x - hv * c2.y) * qsc);
          o[jj + 32] = f2bf((hv * c2.x + lo * c2.y) * qsc);
        }
      }
    }
  } else {
#pragma unroll
    for (int mf = 0; mf < 8; ++mf) {
      const int row0 = m0 + wr * 128 + mf * 16 + (lane >> 4) * 4;
      const int b = row0 >> 11, s0r = row0 & 2047;
#pragma unroll
      for (int nf = 0; nf < 4; ++nf) {
        const int d = nf * 16 + ar;
        unsigned short* o = vt + ((size_t)((b * 16 + h) * 64 + d)) * 2048 + s0r;
        short4v pk;
#pragma unroll
        for (int j = 0; j < 4; ++j) pk[j] = (short)f2bf(acc[mf][nf][j]);
        *(short4v*)o = pk;
      }
    }
  }
#undef CHUNK
#undef STAGE8
#undef FRAG8
#undef PHASE8
}

// ---------------- attention: LDS-staged, counted-vmcnt pipeline (T4) ----------
__device__ __forceinline__ bf16x8 buildP(const unsigned* w, int tt, int hi) {
  const int base = (tt & 1) * 4 + (tt >> 1) * 8;
  unsigned wA = w[base], wB = w[base + 1], wC = w[base + 2], wD = w[base + 3];
  unsigned s1v = __shfl_xor(hi ? wA : wC, 32);
  unsigned s2v = __shfl_xor(hi ? wB : wD, 32);
  union { unsigned u[4]; bf16x8 v; } pw;
  pw.u[0] = hi ? s1v : wA;
  pw.u[1] = hi ? s2v : wB;
  pw.u[2] = hi ? wC : s1v;
  pw.u[3] = hi ? wD : s2v;
  return pw.v;
}

__device__ __forceinline__ void stage_tiles(const char* kg, const char* vg, int t,
                                            unsigned short* kb, unsigned short* vb,
                                            int wv, int lane) {
  const int lsw = ((lane >> 3) & 7) << 4;
#pragma unroll
  for (int p = 0; p < 2; ++p) {
    const int i = 2 * wv + p;
    const int d = i * 1024 + lane * 16;
    async_load16(kg + (size_t)t * 8192 + (d ^ lsw), (char*)kb + i * 1024);
    const int dim = i * 8 + (lane >> 3);
    const int key2 = (((lane & 7) ^ ((lane >> 3) & 7)) << 4);
    async_load16(vg + (size_t)dim * 4096 + (size_t)t * 128 + key2, (char*)vb + i * 1024);
  }
}

__device__ __forceinline__ void super_lds(const unsigned short* kbuf, const unsigned short* vbuf,
                                          int ql, int hi, int off, const bf16x8 (&qf)[4],
                                          f32x16& a0, f32x16& a1, float& m_run, float& l_run) {
  const char* kb = (const char*)kbuf;
  const char* vb = (const char*)vbuf;
  const int rsw = (ql & 7) << 4;
  bf16x8 k0[4], k1[4];
#pragma unroll
  for (int s = 0; s < 4; ++s) {
    k0[s] = *(const bf16x8*)(kb + (((ql << 7) + (s << 5) + (hi << 4)) ^ rsw));
    k1[s] = *(const bf16x8*)(kb + ((((32 + ql) << 7) + (s << 5) + (hi << 4)) ^ rsw));
  }
  f32x16 s0 = zero16(), s1 = zero16();
  __builtin_amdgcn_s_setprio(1);
#pragma unroll
  for (int s = 0; s < 4; ++s) {
    s0 = MFMA32(k0[s], qf[s], s0);
    s1 = MFMA32(k1[s], qf[s], s1);
  }
  __builtin_amdgcn_s_setprio(0);

  bf16x8 v0[4], v1[4];
#pragma unroll
  for (int tt = 0; tt < 4; ++tt) {
    v0[tt] = *(const bf16x8*)(vb + (((ql << 7) + (tt << 5) + (hi << 4)) ^ rsw));
    v1[tt] = *(const bf16x8*)(vb + ((((32 + ql) << 7) + (tt << 5) + (hi << 4)) ^ rsw));
  }

  if (off < 64) {
#pragma unroll
    for (int r = 0; r < 16; ++r) {
      const int key = (r & 3) + 8 * (r >> 2) + 4 * hi;
      if (key > off + ql) s0[r] = -INFINITY;
      if (key + 32 > off + ql) s1[r] = -INFINITY;
    }
  }

  float p[8];
#pragma unroll
  for (int i = 0; i < 8; ++i)
    p[i] = fmaxf(fmaxf(s0[2 * i], s0[2 * i + 1]), fmaxf(s1[2 * i], s1[2 * i + 1]));
#pragma unroll
  for (int i = 0; i < 4; ++i) p[i] = fmaxf(p[i], p[i + 4]);
  float mx = fmaxf(fmaxf(p[0], p[1]), fmaxf(p[2], p[3]));
  mx = fmaxf(mx, __shfl_xor(mx, 32));
  const bool defer = __all(mx - m_run <= 8.0f) != 0;
  const float mn = defer ? m_run : fmaxf(m_run, mx);
  float r0 = 0.f, r1 = 0.f, r2 = 0.f, r3 = 0.f;
#pragma unroll
  for (int i = 0; i < 4; ++i) {
    float e0 = fexp2(s0[4 * i + 0] - mn); s0[4 * i + 0] = e0; r0 += e0;
    float e1 = fexp2(s0[4 * i + 1] - mn); s0[4 * i + 1] = e1; r1 += e1;
    float e2 = fexp2(s0[4 * i + 2] - mn); s0[4 * i + 2] = e2; r2 += e2;
    float e3 = fexp2(s0[4 * i + 3] - mn); s0[4 * i + 3] = e3; r3 += e3;
  }
#pragma unroll
  for (int i = 0; i < 4; ++i) {
    float e0 = fexp2(s1[4 * i + 0] - mn); s1[4 * i + 0] = e0; r0 += e0;
    float e1 = fexp2(s1[4 * i + 1] - mn); s1[4 * i + 1] = e1; r1 += e1;
    float e2 = fexp2(s1[4 * i + 2] - mn); s1[4 * i + 2] = e2; r2 += e2;
    float e3 = fexp2(s1[4 * i + 3] - mn); s1[4 * i + 3] = e3; r3 += e3;
  }
  const float rs = (r0 + r1) + (r2 + r3);
  if (defer) {
    l_run += rs;
  } else {
    const float scl = fexp2(m_run - mn);
    m_run = mn;
    l_run = l_run * scl + rs;
#pragma unroll
    for (int r = 0; r < 16; ++r) { a0[r] *= scl; a1[r] *= scl; }
  }
  unsigned w[16];
#pragma unroll
  for (int i = 0; i < 8; ++i) {
    w[i] = cvt_pk(s0[2 * i], s0[2 * i + 1]);
    w[8 + i] = cvt_pk(s1[2 * i], s1[2 * i + 1]);
  }
  __builtin_amdgcn_s_setprio(1);
#pragma unroll
  for (int tt = 0; tt < 4; ++tt) {
    bf16x8 pp = buildP(w, tt, hi);
    a0 = MFMA32(v0[tt], pp, a0);
    a1 = MFMA32(v1[tt], pp, a1);
  }
  __builtin_amdgcn_s_setprio(0);
}

// Pipeline per tile: stage(t+1) -> vmcnt(4) [stage(t) landed, stage(t+1) stays
// in flight across barriers] -> s_barrier -> compute(t) -> s_barrier [readers
// of buf^1 done before next iter stages into it]. No vmcnt(0) drains.
__global__ __launch_bounds__(256, 3) void attn_kernel(const unsigned short* __restrict__ Q,
                                                      const unsigned short* __restrict__ Kk,
                                                      const unsigned short* __restrict__ Vt,
                                                      unsigned short* __restrict__ O) {
  const int S = 2048;
  const int tid = threadIdx.x, lane = tid & 63, wv = tid >> 6;
  const int xcd = blockIdx.x & 7;
  const int i = blockIdx.x >> 3;
  const int r = i >> 5, j = i & 31;
  const int jb = j >> 4, jq = j & 15;
  const int bh = xcd * 8 + 2 * r + jb;
  const int qb = (r & 1) ? 15 - jq : jq;
  const int b = bh >> 4, h = bh & 15;
  const int ql = lane & 31, hi = lane >> 5;
  const int qlow = qb * 128 + wv * 32;

  __shared__ unsigned short kbuf[2][4096];
  __shared__ unsigned short vbuf[2][4096];

  const unsigned short* qh = Q + (size_t)bh * S * 64;
  const char* kg = (const char*)(Kk + (size_t)bh * S * 64);
  const char* vg = (const char*)(Vt + (size_t)bh * 64 * S);

  bf16x8 qf[4];
#pragma unroll
  for (int s = 0; s < 4; ++s)
    qf[s] = *(const bf16x8*)&qh[(size_t)(qlow + ql) * 64 + s * 16 + hi * 8];

  f32x16 a0 = zero16(), a1 = zero16();
  float m_run = -INFINITY, l_run = 0.f;

  const int nt = 2 * qb + 2;
  stage_tiles(kg, vg, 0, &kbuf[0][0], &vbuf[0][0], wv, lane);
  int buf = 0;
  for (int t = 0; t < nt; ++t) {
    if (t + 1 < nt) {
      stage_tiles(kg, vg, t + 1, &kbuf[buf ^ 1][0], &vbuf[buf ^ 1][0], wv, lane);
      asm volatile("s_waitcnt vmcnt(4)" ::: "memory");  // stage(t) landed
    } else {
      asm volatile("s_waitcnt vmcnt(0)" ::: "memory");
    }
    __builtin_amdgcn_s_barrier();
    if (t * 64 <= qlow + 31) {
      const int off = qlow - t * 64;
      super_lds(&kbuf[buf][0], &vbuf[buf][0], ql, hi, off, qf, a0, a1, m_run, l_run);
    }
    __builtin_amdgcn_s_barrier();
    buf ^= 1;
  }

  l_run += __shfl_xor(l_run, 32);
  const float inv = 1.f / l_run;
  unsigned short* orow = O + (size_t)(b * S + qlow + ql) * 1024 + h * 64;
#pragma unroll
  for (int r2 = 0; r2 < 16; ++r2) {
    int d = (r2 & 3) + 8 * (r2 >> 2) + 4 * hi;
    orow[d] = f2bf(a0[r2] * inv);
    orow[32 + d] = f2bf(a1[r2] * inv);
  }
}

extern "C" void kernel_launch(void* const* d_in, const int* in_sizes, int n_in,
                              void* d_out, int out_size, void* d_ws, size_t ws_size,
                              hipStream_t stream) {
  const float* x = (const float*)d_in[0];
  const float* Wqkv = (const float*)d_in[1];
  const float* Wout = (const float*)d_in[2];
  float* out = (float*)d_out;

  char* ws = (char*)d_ws;
  size_t off = 0;
  auto take = [&](size_t bytes) {
    void* p = ws + off;
    off += (bytes + 255) & ~(size_t)255;
    return p;
  };
  float2* cs = (float2*)take((size_t)2048 * 32 * 8);
  unsigned short* xbf = (unsigned short*)take((size_t)8192 * 1024 * 2);
  unsigned short* wqkvT = (unsigned short*)take((size_t)3072 * 1024 * 2);
  unsigned short* woutT = (unsigned short*)take((size_t)1024 * 1024 * 2);
  unsigned short* qb_ = (unsigned short*)take((size_t)64 * 2048 * 64 * 2);
  unsigned short* kb_ = (unsigned short*)take((size_t)64 * 2048 * 64 * 2);
  unsigned short* vt = (unsigned short*)take((size_t)64 * 64 * 2048 * 2);
  unsigned short* attn = (unsigned short*)take((size_t)8192 * 1024 * 2);

  rope_table_kernel<<<256, 256, 0, stream>>>(cs);
  cvt_kernel<<<(2097152 + 255) / 256, 256, 0, stream>>>(x, xbf, 2097152);
  {
    dim3 g(96, 32);
    transpose_cvt<<<g, 256, 0, stream>>>(Wqkv, wqkvT, 1024, 3072);
  }
  {
    dim3 g(32, 32);
    transpose_cvt<<<g, 256, 0, stream>>>(Wout, woutT, 1024, 1024);
  }
  {
    dim3 g(12, 32);   // N/256, M/256
    gemm8p<<<g, 512, 0, stream>>>(xbf, wqkvT, qb_, kb_, vt, cs, 8192, 3072, 1024);
  }
  attn_kernel<<<1024, 256, 0, stream>>>(qb_, kb_, vt, attn);
  {
    dim3 g(8, 64);
    gemm_bt<<<g, 256, 0, stream>>>(attn, woutT, out, 8192, 1024, 1024);
  }
}